// Round 15
// baseline (120.981 us; speedup 1.0000x reference)
//
#include <hip/hip_runtime.h>
#include <hip/hip_bf16.h>
#include <math.h>

// Problem constants
constexpr int DM = 1024;
constexpr int SEQ = 2048;
constexpr int BATCH = 2;
constexpr int NH = 16;
constexpr int DH = 64;
constexpr int MROWS = BATCH * SEQ;  // 4096
constexpr float SCALE = 0.125f;

typedef __attribute__((ext_vector_type(8))) short short8;
typedef __attribute__((ext_vector_type(4))) float f32x4;
typedef unsigned short ushort_t;

__device__ __forceinline__ unsigned short f2b(float f) {
    __hip_bfloat16 h = __float2bfloat16(f);
    return __builtin_bit_cast(unsigned short, h);
}
__device__ __forceinline__ float b2f(unsigned short u) {
    unsigned int t = ((unsigned int)u) << 16;
    return __builtin_bit_cast(float, t);
}
// v_cvt_pk_bf16_f32: D = {bf16(hi) : bf16(lo)} (no builtin on gfx950 -> asm)
__device__ __forceinline__ unsigned int cvtpk_bf16(float lo, float hi) {
    unsigned int r;
    asm("v_cvt_pk_bf16_f32 %0, %1, %2" : "=v"(r) : "v"(lo), "v"(hi));
    return r;
}
// v_mfma_f32_16x16x16_bf16: A,B = 4 bf16 (2 VGPRs); C/D = 4 f32.
__device__ __forceinline__ f32x4 mfma16_bf16(uint2 a, uint2 b, f32x4 c) {
    asm("v_mfma_f32_16x16x16_bf16 %0, %1, %2, %0"
        : "+v"(c) : "v"(a), "v"(b));
    return c;
}

__device__ __forceinline__ void gload16(const ushort_t* g, ushort_t* l) {
    __builtin_amdgcn_global_load_lds(
        (const __attribute__((address_space(1))) void*)g,
        (__attribute__((address_space(3))) void*)l, 16, 0, 0);
}

// ---------------- merged converter: x -> bf16, W -> transposed bf16 ---------
// blocks [0, 2048): conv_x; blocks [2048, 3072): conv_w (16 x 16 x 4).
__global__ __launch_bounds__(256) void conv_all(
    const float* __restrict__ x, ushort_t* __restrict__ xb,
    const float* __restrict__ Wq, const float* __restrict__ Wk,
    const float* __restrict__ Wv, const float* __restrict__ Wo,
    ushort_t* __restrict__ Wqt, ushort_t* __restrict__ Wkt,
    ushort_t* __restrict__ Wvt, ushort_t* __restrict__ Wot) {
    const int bid = blockIdx.x;
    if (bid < 2048) {
        const size_t idx = (size_t)bid * 256 + threadIdx.x;
        const float4* src = (const float4*)(x + idx * 8);
        float4 a = src[0], b = src[1];
        short8 v;
        v[0] = (short)f2b(a.x); v[1] = (short)f2b(a.y);
        v[2] = (short)f2b(a.z); v[3] = (short)f2b(a.w);
        v[4] = (short)f2b(b.x); v[5] = (short)f2b(b.y);
        v[6] = (short)f2b(b.z); v[7] = (short)f2b(b.w);
        *(short8*)(xb + idx * 8) = v;
        return;
    }
    const int wid = bid - 2048;
    const int z = wid >> 8;
    const int rem = wid & 255;
    const float* W; ushort_t* Wt;
    switch (z) {
        case 0:  W = Wq; Wt = Wqt; break;
        case 1:  W = Wk; Wt = Wkt; break;
        case 2:  W = Wv; Wt = Wvt; break;
        default: W = Wo; Wt = Wot; break;
    }
    __shared__ float L[64][65];
    const int n0 = (rem & 15) * 64, k0 = (rem >> 4) * 64;
    const int t = threadIdx.x;
    const int tr = t >> 4, tc4 = (t & 15) * 4;
#pragma unroll
    for (int i = 0; i < 4; ++i) {
        int kk = tr + i * 16;
        float4 v = *(const float4*)&W[(size_t)(k0 + kk) * DM + n0 + tc4];
        L[kk][tc4 + 0] = v.x; L[kk][tc4 + 1] = v.y;
        L[kk][tc4 + 2] = v.z; L[kk][tc4 + 3] = v.w;
    }
    __syncthreads();
#pragma unroll
    for (int i = 0; i < 4; ++i) {
        int nn = tr + i * 16;
        ushort4 u;
        u.x = f2b(L[tc4 + 0][nn]); u.y = f2b(L[tc4 + 1][nn]);
        u.z = f2b(L[tc4 + 2][nn]); u.w = f2b(L[tc4 + 3][nn]);
        *(ushort4*)&Wt[(size_t)(n0 + nn) * DM + k0 + tc4] = u;
    }
}

// ---------------- GEMM common: BK=32, superrow-swizzled LDS ------------------
// LDS superrow swizzle: buffer = 64 superrows (2 rows) x 8 slots x 16B.
// Element (r, c16) at slot p = (((r&1)<<2)|c16) ^ ((r>>1)&7).
#define BM 128
#define BN 128
#define BKK 32
#define NKT (DM / BKK)   // 32

__device__ __forceinline__ void stage_tile(const ushort_t* __restrict__ A,
                                           const ushort_t* __restrict__ B,
                                           int row0, int col0, int kt,
                                           ushort_t* As, ushort_t* Bs, int tid) {
#pragma unroll
    for (int i = 0; i < 2; ++i) {
        int f = i * 256 + tid;                    // [0,512)
        int sr = f >> 3, p = f & 7;
        int u = p ^ (sr & 7);
        int r = 2 * sr + (u >> 2);                // inverse-swizzled source
        int c = u & 3;
        gload16(&A[(size_t)(row0 + r) * DM + kt * BKK + c * 8], &As[f * 8]);
        gload16(&B[(size_t)(col0 + r) * DM + kt * BKK + c * 8], &Bs[f * 8]);
    }
}

// Triple-buffered counted-vmcnt core (used by out_gemm).
__device__ __forceinline__ void mfma_core(const ushort_t* __restrict__ A,
                                          const ushort_t* __restrict__ B,
                                          int row0, int col0,
                                          ushort_t* smem, f32x4 (&acc)[4][4]) {
    const int tid = threadIdx.x;
    const int wave = tid >> 6, lane = tid & 63;
    const int lg = lane >> 4, ln = lane & 15;
    const int wr = wave >> 1, wc = wave & 1;

    stage_tile(A, B, row0, col0, 0, smem, smem + 4096, tid);
    __builtin_amdgcn_sched_barrier(0);
    stage_tile(A, B, row0, col0, 1, smem + 8192, smem + 12288, tid);

    for (int kt = 0; kt < NKT; ++kt) {
        if (kt + 1 < NKT)
            asm volatile("s_waitcnt vmcnt(4)" ::: "memory");
        else
            asm volatile("s_waitcnt vmcnt(0)" ::: "memory");
        __builtin_amdgcn_s_barrier();

        if (kt + 2 < NKT) {
            ushort_t* An = smem + ((kt + 2) % 3) * 8192;
            stage_tile(A, B, row0, col0, kt + 2, An, An + 4096, tid);
        }

        const ushort_t* As = smem + (kt % 3) * 8192;
        const ushort_t* Bs = As + 4096;
        short8 af[4], bf[4];
#pragma unroll
        for (int mi = 0; mi < 4; ++mi) {
            int r = wr * 64 + mi * 16 + ln;
            int sr = r >> 1;
            int p = (((r & 1) << 2) | lg) ^ (sr & 7);
            af[mi] = *(const short8*)&As[sr * 64 + p * 8];
        }
#pragma unroll
        for (int ni = 0; ni < 4; ++ni) {
            int r = wc * 64 + ni * 16 + ln;
            int sr = r >> 1;
            int p = (((r & 1) << 2) | lg) ^ (sr & 7);
            bf[ni] = *(const short8*)&Bs[sr * 64 + p * 8];
        }
        __builtin_amdgcn_s_setprio(1);
#pragma unroll
        for (int mi = 0; mi < 4; ++mi)
#pragma unroll
            for (int ni = 0; ni < 4; ++ni)
                acc[mi][ni] = __builtin_amdgcn_mfma_f32_16x16x32_bf16(
                    af[mi], bf[ni], acc[mi][ni], 0, 0, 0);
        __builtin_amdgcn_s_setprio(0);
    }
}

// ---------------- FUSED QKV GEMM: one block computes Cq, Ck, Cv -------------
// A (xb tile) staged ONCE per K-step and reused by all three outputs:
// per wave-step 16 ds_read_b128 feed 48 MFMAs (3:1 vs 2:1 split kernels).
// Grid 8x32 = 256 blocks = 1/CU; LDS = 3 stages x (A + Bq + Bk + Bv) = 96 KB.
// vmcnt: 8 loads/stage/wave; wait vmcnt(8) = stage t landed, t+1 in flight.
__global__ __launch_bounds__(256) void mfma_gemm_qkv_fused(
    const ushort_t* __restrict__ xb, const ushort_t* __restrict__ Wt3,
    const float* __restrict__ bq, const float* __restrict__ bk,
    const float* __restrict__ bv,
    ushort_t* __restrict__ qb, ushort_t* __restrict__ kb,
    ushort_t* __restrict__ vtb) {
    constexpr size_t WSZ = (size_t)DM * DM;
    const int row0 = blockIdx.y * BM;
    const int col0 = blockIdx.x * BN;
    const int tid = threadIdx.x;
    const int wave = tid >> 6, lane = tid & 63;
    const int lg = lane >> 4, ln = lane & 15;
    const int wr = wave >> 1, wc = wave & 1;

    __shared__ ushort_t smem[3 * 16384];   // 96 KB: 3 stages of 32 KB

    f32x4 acc[3][4][4] = {};

    // ---- stage issuance: A then Bq,Bk,Bv (8 gload16 / thread / stage)
    auto stage = [&](int kt, int s) {
        ushort_t* base = smem + s * 16384;
#pragma unroll
        for (int i = 0; i < 2; ++i) {
            int f = i * 256 + tid;
            int sr = f >> 3, p = f & 7;
            int u = p ^ (sr & 7);
            int r = 2 * sr + (u >> 2);
            int c = u & 3;
            gload16(&xb[(size_t)(row0 + r) * DM + kt * BKK + c * 8], &base[f * 8]);
        }
#pragma unroll
        for (int zz = 0; zz < 3; ++zz)
#pragma unroll
            for (int i = 0; i < 2; ++i) {
                int f = i * 256 + tid;
                int sr = f >> 3, p = f & 7;
                int u = p ^ (sr & 7);
                int r = 2 * sr + (u >> 2);
                int c = u & 3;
                gload16(&Wt3[zz * WSZ + (size_t)(col0 + r) * DM + kt * BKK + c * 8],
                        &base[(1 + zz) * 4096 + f * 8]);
            }
    };

    stage(0, 0);
    __builtin_amdgcn_sched_barrier(0);
    stage(1, 1);

    for (int kt = 0; kt < NKT; ++kt) {
        if (kt + 1 < NKT)
            asm volatile("s_waitcnt vmcnt(8)" ::: "memory");
        else
            asm volatile("s_waitcnt vmcnt(0)" ::: "memory");
        __builtin_amdgcn_s_barrier();

        if (kt + 2 < NKT) stage(kt + 2, (kt + 2) % 3);

        const ushort_t* As = smem + (kt % 3) * 16384;
        short8 af[4];
#pragma unroll
        for (int mi = 0; mi < 4; ++mi) {
            int r = wr * 64 + mi * 16 + ln;
            int sr = r >> 1;
            int p = (((r & 1) << 2) | lg) ^ (sr & 7);
            af[mi] = *(const short8*)&As[sr * 64 + p * 8];
        }
#pragma unroll
        for (int zz = 0; zz < 3; ++zz) {
            const ushort_t* Bs = As + (1 + zz) * 4096;
            short8 bf[4];
#pragma unroll
            for (int ni = 0; ni < 4; ++ni) {
                int r = wc * 64 + ni * 16 + ln;
                int sr = r >> 1;
                int p = (((r & 1) << 2) | lg) ^ (sr & 7);
                bf[ni] = *(const short8*)&Bs[sr * 64 + p * 8];
            }
            __builtin_amdgcn_s_setprio(1);
#pragma unroll
            for (int mi = 0; mi < 4; ++mi)
#pragma unroll
                for (int ni = 0; ni < 4; ++ni)
                    acc[zz][mi][ni] = __builtin_amdgcn_mfma_f32_16x16x32_bf16(
                        af[mi], bf[ni], acc[zz][mi][ni], 0, 0, 0);
            __builtin_amdgcn_s_setprio(0);
        }
    }

    // ---- epilogue: three sequential Cs passes (bias, RoPE for q/k, V^T)
    ushort_t* Cs = smem;   // 32 KB, aliases stage 0
#pragma unroll
    for (int zz = 0; zz < 3; ++zz) {
        const float* bias = (zz == 0) ? bq : (zz == 1) ? bk : bv;
        const bool isV = (zz == 2);
        __syncthreads();   // previous pass done reading / MFMA done reading As
#pragma unroll
        for (int mi = 0; mi < 4; ++mi)
#pragma unroll
            for (int ni = 0; ni < 4; ++ni)
#pragma unroll
                for (int r = 0; r < 4; ++r) {
                    int mrel = wr * 64 + mi * 16 + lg * 4 + r;
                    int nrel = wc * 64 + ni * 16 + ln;
                    float v = acc[zz][mi][ni][r] + bias[col0 + nrel];
                    Cs[isV ? (nrel * 128 + mrel) : (mrel * 128 + nrel)] = f2b(v);
                }
        __syncthreads();

        if (!isV) {
            ushort_t* out = (zz == 0) ? qb : kb;
#pragma unroll
            for (int i = 0; i < 8; ++i) {
                int f = i * 256 + tid;
                int rrow = f >> 4, c8 = f & 15;
                int m = row0 + rrow;
                int b = m >> 11, s = m & (SEQ - 1);
                int n = col0 + c8 * 8;
                int h = n >> 6, d = n & 63;
                short8 val;
                if (d < 16) {
                    const ushort_t* base = &Cs[rrow * 128 + (c8 & 8) * 8];
                    const bool hi = (d >= 8);
#pragma unroll
                    for (int j = 0; j < 8; ++j) {
                        float t1 = b2f(base[j]);
                        float t2 = b2f(base[8 + j]);
                        float invf = __expf(-(float)j * 1.1512925465f); // ln(1e4)/8
                        float ang = (float)s * invf;
                        float c_, si_;
                        __sincosf(ang, &si_, &c_);
                        val[j] = (short)f2b(hi ? (t1 * si_ + t2 * c_)
                                               : (t1 * c_ - t2 * si_));
                    }
                } else {
                    val = *(const short8*)&Cs[rrow * 128 + c8 * 8];
                }
                *(short8*)&out[((size_t)((b * NH + h) * SEQ) + s) * DH + d] = val;
            }
        } else {
#pragma unroll
            for (int i = 0; i < 8; ++i) {
                int f = i * 256 + tid;
                int nrow = f >> 4, c8 = f & 15;
                int n = col0 + nrow;
                int h = n >> 6, d = n & 63;
                int m = row0 + c8 * 8;
                int b = m >> 11, s = m & (SEQ - 1);
                *(short8*)&vtb[((size_t)((b * NH + h) * DH) + d) * SEQ + s] =
                    *(const short8*)&Cs[nrow * 128 + c8 * 8];
            }
        }
    }
}

// Output projection: A = ctxb bf16 [M][DM], B = Wot, out fp32 [M][DM] + bo.
__global__ __launch_bounds__(256) void mfma_gemm_out(
    const ushort_t* __restrict__ ctxb, const ushort_t* __restrict__ Wot,
    const float* __restrict__ bo, float* __restrict__ out) {
    const int row0 = blockIdx.y * BM;
    const int col0 = blockIdx.x * BN;
    __shared__ ushort_t smem[24576];
    f32x4 acc[4][4] = {};
    mfma_core(ctxb, Wot, row0, col0, smem, acc);

    const int tid = threadIdx.x;
    const int wave = tid >> 6, lane = tid & 63;
    const int lg = lane >> 4, ln = lane & 15;
    const int wr = wave >> 1, wc = wave & 1;
#pragma unroll
    for (int mi = 0; mi < 4; ++mi)
#pragma unroll
        for (int ni = 0; ni < 4; ++ni)
#pragma unroll
            for (int r = 0; r < 4; ++r) {
                int m = row0 + wr * 64 + mi * 16 + lg * 4 + r;
                int n = col0 + wc * 64 + ni * 16 + ln;
                out[(size_t)m * DM + n] = acc[mi][ni][r] + bo[n];
            }
}

// ---------------- Causal flash attention, k-split partials (round-10) -------
// Fixed-max softmax => partial (o, l) over disjoint key ranges are ADDITIVE.
//   y in [0,16):  qt = 16+y,  tiles [0,16)      -> partial chunk 0
//   y in [16,32): qt = 47-y,  tiles [16,qt+1)   -> partial chunk 1
//   y in [32,48): qt = 47-y,  tiles [0,qt+1)    -> direct ctx write
#define AQT 64
#define AKT 64
#define NQT (SEQ / AQT)   // 32

__global__ __launch_bounds__(256) void attn_mfma(
    const ushort_t* __restrict__ qb, const ushort_t* __restrict__ kb,
    const ushort_t* __restrict__ vtb, ushort_t* __restrict__ ctxb,
    ushort_t* __restrict__ opart, float* __restrict__ lpart) {
    constexpr float C1 = 0.18033688f;        // SCALE * log2(e)
    constexpr float M2 = 1.44269504f;        // C1 * 8 (score bound 8 sigma)
    const int bh = blockIdx.x;
    const int y = blockIdx.y;

    int qt, t0, t1, chunk;
    if (y < 16)      { qt = 16 + y;  t0 = 0;  t1 = 16;     chunk = 0; }
    else if (y < 32) { qt = 47 - y;  t0 = 16; t1 = qt + 1; chunk = 1; }
    else             { qt = 47 - y;  t0 = 0;  t1 = qt + 1; chunk = -1; }
    const int q0 = qt * AQT;

    const int tid = threadIdx.x;
    const int wave = tid >> 6;
    const int lane = tid & 63;
    const int lg = lane >> 4;
    const int ln = lane & 15;

    __shared__ ushort_t KT[2][64 * 64];
    __shared__ ushort_t VT[2][64 * 64];

    const ushort_t* kbase = kb + (size_t)bh * SEQ * DH;
    const ushort_t* vbase = vtb + (size_t)bh * DH * SEQ;
    const int b = bh >> 4, h = bh & 15;

    const ushort_t* qrow = qb + ((size_t)bh * SEQ + q0 + wave * 16 + ln) * DH;
    short8 qf0 = *(const short8*)&qrow[lg * 8];
    short8 qf1 = *(const short8*)&qrow[32 + lg * 8];

    f32x4 o[4];
#pragma unroll
    for (int nt = 0; nt < 4; nt++) o[nt] = f32x4{0.f, 0.f, 0.f, 0.f};
    float l = 0.f;                        // per-lane partial for q-row = ln

    // prologue: stage tile t0 into buffer 0
#pragma unroll
    for (int i = 0; i < 2; i++) {
        int f = i * 256 + tid;
        int r = f >> 3, p = f & 7, c = p ^ (r & 7);
        gload16(&kbase[(size_t)(t0 * AKT + r) * DH + c * 8], &KT[0][f * 8]);
        gload16(&vbase[(size_t)r * SEQ + t0 * AKT + c * 8], &VT[0][f * 8]);
    }

    int cur = 0;
    for (int t = t0; t < t1; ++t) {
        __syncthreads();   // staged data for tile t visible

        if (t + 1 < t1) {
            const int nb0 = (t + 1) * AKT;
            const int nxt = cur ^ 1;
#pragma unroll
            for (int i = 0; i < 2; i++) {
                int f = i * 256 + tid;
                int r = f >> 3, p = f & 7, c = p ^ (r & 7);
                gload16(&kbase[(size_t)(nb0 + r) * DH + c * 8], &KT[nxt][f * 8]);
                gload16(&vbase[(size_t)r * SEQ + nb0 + c * 8], &VT[nxt][f * 8]);
            }
        }

        // ---- swapped QK^T: st[kt][r] = S[key=16kt+lg*4+r][q=ln]
        float st[4][4];
        __builtin_amdgcn_s_setprio(1);
#pragma unroll
        for (int kt = 0; kt < 4; kt++) {
            f32x4 acc = f32x4{0.f, 0.f, 0.f, 0.f};
            int krow = kt * 16 + ln;
            short8 b0 = *(const short8*)&KT[cur][krow * 64 + ((lg ^ (krow & 7)) * 8)];
            short8 b1 = *(const short8*)&KT[cur][krow * 64 + (((4 + lg) ^ (krow & 7)) * 8)];
            acc = __builtin_amdgcn_mfma_f32_16x16x32_bf16(b0, qf0, acc, 0, 0, 0);
            acc = __builtin_amdgcn_mfma_f32_16x16x32_bf16(b1, qf1, acc, 0, 0, 0);
#pragma unroll
            for (int r = 0; r < 4; r++) st[kt][r] = acc[r];
        }
        __builtin_amdgcn_s_setprio(0);

        // causal mask only on the diagonal tile (t == qt; never in chunk 0)
        if (t == qt) {
            const int qrel = wave * 16 + ln;
#pragma unroll
            for (int kt = 0; kt < 4; kt++)
#pragma unroll
                for (int r = 0; r < 4; r++)
                    if (kt * 16 + lg * 4 + r > qrel) st[kt][r] = -1e30f;
        }

        // ---- fixed-max softmax: p = exp2(C1*s - M2); P packed in registers
        uint2 pkq[4];
#pragma unroll
        for (int kt = 0; kt < 4; kt++) {
            float pv[4];
#pragma unroll
            for (int r = 0; r < 4; r++) {
                pv[r] = exp2f(fmaf(C1, st[kt][r], -M2));
                l += pv[r];
            }
            pkq[kt].x = cvtpk_bf16(pv[0], pv[1]);
            pkq[kt].y = cvtpk_bf16(pv[2], pv[3]);
        }

        // ---- PV: o[nt] += P(16x16 A-frag, reg) x V^T(8B LDS reads)
        __builtin_amdgcn_s_setprio(1);
#pragma unroll
        for (int nt = 0; nt < 4; nt++) {
            int vrow = nt * 16 + ln;
#pragma unroll
            for (int kt = 0; kt < 4; kt++) {
                int chunk16 = (2 * kt + (lg >> 1)) ^ (vrow & 7);
                uint2 vb = *(const uint2*)&VT[cur][vrow * 64 + chunk16 * 8 + (lg & 1) * 4];
                o[nt] = mfma16_bf16(pkq[kt], vb, o[nt]);
            }
        }
        __builtin_amdgcn_s_setprio(0);

        cur ^= 1;
    }

    // ---- epilogue
    l += __shfl_xor(l, 16);
    l += __shfl_xor(l, 32);

    if (chunk >= 0) {
        // partial: write bf16 o (undivided) + f32 l
        const int pid = ((bh << 4) + (qt - 16)) * 2 + chunk;
        if (lg == 0) lpart[pid * 64 + wave * 16 + ln] = l;
        ushort_t* ob = opart + (size_t)pid * 4096;
#pragma unroll
        for (int r = 0; r < 4; r++) {
            int qrel = wave * 16 + lg * 4 + r;
#pragma unroll
            for (int nt = 0; nt < 4; nt++)
                ob[qrel * 64 + nt * 16 + ln] = f2b(o[nt][r]);
        }
    } else {
        const float rcp = 1.f / l;
#pragma unroll
        for (int r = 0; r < 4; r++) {
            float invl = __shfl(rcp, (lane & 48) | (lg * 4 + r));
            int qg = q0 + wave * 16 + lg * 4 + r;
            ushort_t* op = ctxb + ((size_t)(b * SEQ + qg)) * DM + h * DH;
#pragma unroll
            for (int nt = 0; nt < 4; nt++)
                op[nt * 16 + ln] = f2b(o[nt][r] * invl);
        }
    }
}

// Combine the two partials for qt >= 16: ctx = (o0 + o1) / (l0 + l1).
__global__ __launch_bounds__(256) void attn_reduce(
    const ushort_t* __restrict__ opart, const float* __restrict__ lpart,
    ushort_t* __restrict__ ctxb) {
    const int bh = blockIdx.x;             // 0..31
    const int qt = 16 + blockIdx.y;        // 16..31
    const int tid = threadIdx.x;
    const int q = tid >> 2;                // 0..63
    const int d0 = (tid & 3) * 16;         // 0,16,32,48

    const int pid0 = ((bh << 4) + (qt - 16)) * 2;
    const ushort_t* o0 = opart + (size_t)pid0 * 4096 + q * 64 + d0;
    const ushort_t* o1 = opart + (size_t)(pid0 + 1) * 4096 + q * 64 + d0;
    const float inv = 1.f / (lpart[pid0 * 64 + q] + lpart[(pid0 + 1) * 64 + q]);

    const int b = bh >> 4, h = bh & 15;
    ushort_t* op = ctxb + ((size_t)(b * SEQ + qt * 64 + q)) * DM + h * DH + d0;
#pragma unroll
    for (int half = 0; half < 2; ++half) {
        short8 a = *(const short8*)&o0[half * 8];
        short8 c = *(const short8*)&o1[half * 8];
        short8 r;
#pragma unroll
        for (int j = 0; j < 8; ++j)
            r[j] = (short)f2b((b2f((unsigned short)a[j]) +
                               b2f((unsigned short)c[j])) * inv);
        *(short8*)&op[half * 8] = r;
    }
}

// ---------------- launch ------------------------------------------------------
extern "C" void kernel_launch(void* const* d_in, const int* in_sizes, int n_in,
                              void* d_out, int out_size, void* d_ws, size_t ws_size,
                              hipStream_t stream) {
    const float* x  = (const float*)d_in[0];
    const float* Wq = (const float*)d_in[1];
    const float* bq = (const float*)d_in[2];
    const float* Wk = (const float*)d_in[3];
    const float* bk = (const float*)d_in[4];
    const float* Wv = (const float*)d_in[5];
    const float* bv = (const float*)d_in[6];
    const float* Wo = (const float*)d_in[7];
    const float* bo = (const float*)d_in[8];
    float* out = (float*)d_out;

    constexpr size_t TSZ = (size_t)MROWS * DM;   // 4194304
    constexpr size_t WSZ = (size_t)DM * DM;      // 1048576
    ushort_t* xb  = (ushort_t*)d_ws;
    ushort_t* Wqt = xb + TSZ;
    ushort_t* Wkt = Wqt + WSZ;
    ushort_t* Wvt = Wkt + WSZ;
    ushort_t* Wot = Wvt + WSZ;
    ushort_t* qbp = Wot + WSZ;
    ushort_t* kbp = qbp + TSZ;
    ushort_t* vtp = kbp + TSZ;
    ushort_t* ctxb = vtp + TSZ;

    // attn partials alias regions dead by the time attn runs.
    ushort_t* opart = xb;
    float* lpart = (float*)Wqt;

    conv_all<<<3072, 256, 0, stream>>>(x, xb, Wq, Wk, Wv, Wo, Wqt, Wkt, Wvt, Wot);

    // fused QKV: Wqt/Wkt/Wvt are contiguous at Wqt (stride WSZ)
    mfma_gemm_qkv_fused<<<dim3(DM / BN, MROWS / BM), 256, 0, stream>>>(
        xb, Wqt, bq, bk, bv, qbp, kbp, vtp);

    attn_mfma<<<dim3(BATCH * NH, 48), 256, 0, stream>>>(
        qbp, kbp, vtp, ctxb, opart, lpart);
    attn_reduce<<<dim3(BATCH * NH, 16), 256, 0, stream>>>(opart, lpart, ctxb);

    mfma_gemm_out<<<dim3(DM / BN, MROWS / BM), 256, 0, stream>>>(ctxb, Wot, bo, out);
}

// Round 16
// 115.028 us; speedup vs baseline: 1.0518x; 1.0518x over previous
//
#include <hip/hip_runtime.h>
#include <hip/hip_bf16.h>
#include <math.h>

// Problem constants
constexpr int DM = 1024;
constexpr int SEQ = 2048;
constexpr int BATCH = 2;
constexpr int NH = 16;
constexpr int DH = 64;
constexpr int MROWS = BATCH * SEQ;  // 4096
constexpr float SCALE = 0.125f;

typedef __attribute__((ext_vector_type(8))) short short8;
typedef __attribute__((ext_vector_type(4))) float f32x4;
typedef unsigned short ushort_t;

__device__ __forceinline__ unsigned short f2b(float f) {
    __hip_bfloat16 h = __float2bfloat16(f);
    return __builtin_bit_cast(unsigned short, h);
}
__device__ __forceinline__ float b2f(unsigned short u) {
    unsigned int t = ((unsigned int)u) << 16;
    return __builtin_bit_cast(float, t);
}
// v_cvt_pk_bf16_f32: D = {bf16(hi) : bf16(lo)} (no builtin on gfx950 -> asm)
__device__ __forceinline__ unsigned int cvtpk_bf16(float lo, float hi) {
    unsigned int r;
    asm("v_cvt_pk_bf16_f32 %0, %1, %2" : "=v"(r) : "v"(lo), "v"(hi));
    return r;
}
// v_mfma_f32_16x16x16_bf16: A,B = 4 bf16 (2 VGPRs); C/D = 4 f32.
__device__ __forceinline__ f32x4 mfma16_bf16(uint2 a, uint2 b, f32x4 c) {
    asm("v_mfma_f32_16x16x16_bf16 %0, %1, %2, %0"
        : "+v"(c) : "v"(a), "v"(b));
    return c;
}

__device__ __forceinline__ void gload16(const ushort_t* g, ushort_t* l) {
    __builtin_amdgcn_global_load_lds(
        (const __attribute__((address_space(1))) void*)g,
        (__attribute__((address_space(3))) void*)l, 16, 0, 0);
}

// ---------------- merged converter: x -> bf16, W -> transposed bf16 ---------
// blocks [0, 2048): conv_x; blocks [2048, 3072): conv_w (16 x 16 x 4).
__global__ __launch_bounds__(256) void conv_all(
    const float* __restrict__ x, ushort_t* __restrict__ xb,
    const float* __restrict__ Wq, const float* __restrict__ Wk,
    const float* __restrict__ Wv, const float* __restrict__ Wo,
    ushort_t* __restrict__ Wqt, ushort_t* __restrict__ Wkt,
    ushort_t* __restrict__ Wvt, ushort_t* __restrict__ Wot) {
    const int bid = blockIdx.x;
    if (bid < 2048) {
        const size_t idx = (size_t)bid * 256 + threadIdx.x;
        const float4* src = (const float4*)(x + idx * 8);
        float4 a = src[0], b = src[1];
        short8 v;
        v[0] = (short)f2b(a.x); v[1] = (short)f2b(a.y);
        v[2] = (short)f2b(a.z); v[3] = (short)f2b(a.w);
        v[4] = (short)f2b(b.x); v[5] = (short)f2b(b.y);
        v[6] = (short)f2b(b.z); v[7] = (short)f2b(b.w);
        *(short8*)(xb + idx * 8) = v;
        return;
    }
    const int wid = bid - 2048;
    const int z = wid >> 8;
    const int rem = wid & 255;
    const float* W; ushort_t* Wt;
    switch (z) {
        case 0:  W = Wq; Wt = Wqt; break;
        case 1:  W = Wk; Wt = Wkt; break;
        case 2:  W = Wv; Wt = Wvt; break;
        default: W = Wo; Wt = Wot; break;
    }
    __shared__ float L[64][65];
    const int n0 = (rem & 15) * 64, k0 = (rem >> 4) * 64;
    const int t = threadIdx.x;
    const int tr = t >> 4, tc4 = (t & 15) * 4;
#pragma unroll
    for (int i = 0; i < 4; ++i) {
        int kk = tr + i * 16;
        float4 v = *(const float4*)&W[(size_t)(k0 + kk) * DM + n0 + tc4];
        L[kk][tc4 + 0] = v.x; L[kk][tc4 + 1] = v.y;
        L[kk][tc4 + 2] = v.z; L[kk][tc4 + 3] = v.w;
    }
    __syncthreads();
#pragma unroll
    for (int i = 0; i < 4; ++i) {
        int nn = tr + i * 16;
        ushort4 u;
        u.x = f2b(L[tc4 + 0][nn]); u.y = f2b(L[tc4 + 1][nn]);
        u.z = f2b(L[tc4 + 2][nn]); u.w = f2b(L[tc4 + 3][nn]);
        *(ushort4*)&Wt[(size_t)(n0 + nn) * DM + k0 + tc4] = u;
    }
}

// ---------------- MFMA GEMM core: 128x128 tile, BK=32, triple-buffered -------
// Counted-vmcnt pipeline (T4): per K-step wait vmcnt(4) (only the OLDEST
// stage drained), raw s_barrier, issue stage kt+2, then ds_read+MFMA.
// LDS superrow swizzle: buffer = 64 superrows (2 rows) x 8 slots x 16B.
#define BM 128
#define BN 128
#define BKK 32
#define NKT (DM / BKK)   // 32

__device__ __forceinline__ void stage_tile(const ushort_t* __restrict__ A,
                                           const ushort_t* __restrict__ B,
                                           int row0, int col0, int kt,
                                           ushort_t* As, ushort_t* Bs, int tid) {
#pragma unroll
    for (int i = 0; i < 2; ++i) {
        int f = i * 256 + tid;                    // [0,512)
        int sr = f >> 3, p = f & 7;
        int u = p ^ (sr & 7);
        int r = 2 * sr + (u >> 2);                // inverse-swizzled source
        int c = u & 3;
        gload16(&A[(size_t)(row0 + r) * DM + kt * BKK + c * 8], &As[f * 8]);
        gload16(&B[(size_t)(col0 + r) * DM + kt * BKK + c * 8], &Bs[f * 8]);
    }
}

__device__ __forceinline__ void mfma_core(const ushort_t* __restrict__ A,
                                          const ushort_t* __restrict__ B,
                                          int row0, int col0,
                                          ushort_t* smem, f32x4 (&acc)[4][4]) {
    const int tid = threadIdx.x;
    const int wave = tid >> 6, lane = tid & 63;
    const int lg = lane >> 4, ln = lane & 15;
    const int wr = wave >> 1, wc = wave & 1;

    stage_tile(A, B, row0, col0, 0, smem, smem + 4096, tid);
    __builtin_amdgcn_sched_barrier(0);
    stage_tile(A, B, row0, col0, 1, smem + 8192, smem + 12288, tid);

    for (int kt = 0; kt < NKT; ++kt) {
        if (kt + 1 < NKT)
            asm volatile("s_waitcnt vmcnt(4)" ::: "memory");
        else
            asm volatile("s_waitcnt vmcnt(0)" ::: "memory");
        __builtin_amdgcn_s_barrier();

        if (kt + 2 < NKT) {
            ushort_t* An = smem + ((kt + 2) % 3) * 8192;
            stage_tile(A, B, row0, col0, kt + 2, An, An + 4096, tid);
        }

        const ushort_t* As = smem + (kt % 3) * 8192;
        const ushort_t* Bs = As + 4096;
        short8 af[4], bf[4];
#pragma unroll
        for (int mi = 0; mi < 4; ++mi) {
            int r = wr * 64 + mi * 16 + ln;
            int sr = r >> 1;
            int p = (((r & 1) << 2) | lg) ^ (sr & 7);
            af[mi] = *(const short8*)&As[sr * 64 + p * 8];
        }
#pragma unroll
        for (int ni = 0; ni < 4; ++ni) {
            int r = wc * 64 + ni * 16 + ln;
            int sr = r >> 1;
            int p = (((r & 1) << 2) | lg) ^ (sr & 7);
            bf[ni] = *(const short8*)&Bs[sr * 64 + p * 8];
        }
        __builtin_amdgcn_s_setprio(1);
#pragma unroll
        for (int mi = 0; mi < 4; ++mi)
#pragma unroll
            for (int ni = 0; ni < 4; ++ni)
                acc[mi][ni] = __builtin_amdgcn_mfma_f32_16x16x32_bf16(
                    af[mi], bf[ni], acc[mi][ni], 0, 0, 0);
        __builtin_amdgcn_s_setprio(0);
    }
}

// QKV: z=0 -> qb [B,H,S,DH]; z=1 -> kb; z=2 -> vtb [B,H,DH,S]; all bf16 +bias.
// Partial RoPE (rot dim 16) fused into the q/k scatter.
__global__ __launch_bounds__(256) void mfma_gemm_qkv(
    const ushort_t* __restrict__ xb,
    const ushort_t* __restrict__ Wqt, const ushort_t* __restrict__ Wkt,
    const ushort_t* __restrict__ Wvt,
    const float* __restrict__ bq, const float* __restrict__ bk,
    const float* __restrict__ bv,
    ushort_t* __restrict__ qb, ushort_t* __restrict__ kb,
    ushort_t* __restrict__ vtb) {
    const ushort_t* W; const float* bias;
    if (blockIdx.z == 0)      { W = Wqt; bias = bq; }
    else if (blockIdx.z == 1) { W = Wkt; bias = bk; }
    else                      { W = Wvt; bias = bv; }

    const int row0 = blockIdx.y * BM;
    const int col0 = blockIdx.x * BN;
    __shared__ ushort_t smem[24576];   // 48 KB: 3 stage buffers; Cs aliases
    f32x4 acc[4][4] = {};
    mfma_core(xb, W, row0, col0, smem, acc);

    const int tid = threadIdx.x;
    const int wave = tid >> 6, lane = tid & 63;
    const int lg = lane >> 4, ln = lane & 15;
    const int wr = wave >> 1, wc = wave & 1;
    const bool isV = (blockIdx.z == 2);

    __syncthreads();
    ushort_t* Cs = smem;
#pragma unroll
    for (int mi = 0; mi < 4; ++mi)
#pragma unroll
        for (int ni = 0; ni < 4; ++ni)
#pragma unroll
            for (int r = 0; r < 4; ++r) {
                int mrel = wr * 64 + mi * 16 + lg * 4 + r;
                int nrel = wc * 64 + ni * 16 + ln;
                float v = acc[mi][ni][r] + bias[col0 + nrel];
                Cs[isV ? (nrel * 128 + mrel) : (mrel * 128 + nrel)] = f2b(v);
            }
    __syncthreads();

    if (!isV) {
        ushort_t* out = (blockIdx.z == 0) ? qb : kb;
#pragma unroll
        for (int i = 0; i < 8; ++i) {
            int f = i * 256 + tid;
            int rrow = f >> 4, c8 = f & 15;
            int m = row0 + rrow;
            int b = m >> 11, s = m & (SEQ - 1);
            int n = col0 + c8 * 8;
            int h = n >> 6, d = n & 63;
            short8 val;
            if (d < 16) {
                const ushort_t* base = &Cs[rrow * 128 + (c8 & 8) * 8];
                const bool hi = (d >= 8);
#pragma unroll
                for (int j = 0; j < 8; ++j) {
                    float t1 = b2f(base[j]);
                    float t2 = b2f(base[8 + j]);
                    float invf = __expf(-(float)j * 1.1512925465f); // ln(1e4)/8
                    float ang = (float)s * invf;
                    float c_, si_;
                    __sincosf(ang, &si_, &c_);
                    val[j] = (short)f2b(hi ? (t1 * si_ + t2 * c_)
                                           : (t1 * c_ - t2 * si_));
                }
            } else {
                val = *(const short8*)&Cs[rrow * 128 + c8 * 8];
            }
            *(short8*)&out[((size_t)((b * NH + h) * SEQ) + s) * DH + d] = val;
        }
    } else {
#pragma unroll
        for (int i = 0; i < 8; ++i) {
            int f = i * 256 + tid;
            int nrow = f >> 4, c8 = f & 15;
            int n = col0 + nrow;
            int h = n >> 6, d = n & 63;
            int m = row0 + c8 * 8;
            int b = m >> 11, s = m & (SEQ - 1);
            *(short8*)&vtb[((size_t)((b * NH + h) * DH) + d) * SEQ + s] =
                *(const short8*)&Cs[nrow * 128 + c8 * 8];
        }
    }
}

// Output projection: A = ctxb bf16 [M][DM], B = Wot, out fp32 [M][DM] + bo.
__global__ __launch_bounds__(256) void mfma_gemm_out(
    const ushort_t* __restrict__ ctxb, const ushort_t* __restrict__ Wot,
    const float* __restrict__ bo, float* __restrict__ out) {
    const int row0 = blockIdx.y * BM;
    const int col0 = blockIdx.x * BN;
    __shared__ ushort_t smem[24576];
    f32x4 acc[4][4] = {};
    mfma_core(ctxb, Wot, row0, col0, smem, acc);

    const int tid = threadIdx.x;
    const int wave = tid >> 6, lane = tid & 63;
    const int lg = lane >> 4, ln = lane & 15;
    const int wr = wave >> 1, wc = wave & 1;
#pragma unroll
    for (int mi = 0; mi < 4; ++mi)
#pragma unroll
        for (int ni = 0; ni < 4; ++ni)
#pragma unroll
            for (int r = 0; r < 4; ++r) {
                int m = row0 + wr * 64 + mi * 16 + lg * 4 + r;
                int n = col0 + wc * 64 + ni * 16 + ln;
                out[(size_t)m * DM + n] = acc[mi][ni][r] + bo[n];
            }
}

// ---------------- Causal flash attention, k-split partials (round-10) -------
// Fixed-max softmax => partial (o, l) over disjoint key ranges are ADDITIVE.
//   y in [0,16):  qt = 16+y,  tiles [0,16)      -> partial chunk 0
//   y in [16,32): qt = 47-y,  tiles [16,qt+1)   -> partial chunk 1
//   y in [32,48): qt = 47-y,  tiles [0,qt+1)    -> direct ctx write
#define AQT 64
#define AKT 64
#define NQT (SEQ / AQT)   // 32

__global__ __launch_bounds__(256) void attn_mfma(
    const ushort_t* __restrict__ qb, const ushort_t* __restrict__ kb,
    const ushort_t* __restrict__ vtb, ushort_t* __restrict__ ctxb,
    ushort_t* __restrict__ opart, float* __restrict__ lpart) {
    constexpr float C1 = 0.18033688f;        // SCALE * log2(e)
    constexpr float M2 = 1.44269504f;        // C1 * 8 (score bound 8 sigma)
    const int bh = blockIdx.x;
    const int y = blockIdx.y;

    int qt, t0, t1, chunk;
    if (y < 16)      { qt = 16 + y;  t0 = 0;  t1 = 16;     chunk = 0; }
    else if (y < 32) { qt = 47 - y;  t0 = 16; t1 = qt + 1; chunk = 1; }
    else             { qt = 47 - y;  t0 = 0;  t1 = qt + 1; chunk = -1; }
    const int q0 = qt * AQT;

    const int tid = threadIdx.x;
    const int wave = tid >> 6;
    const int lane = tid & 63;
    const int lg = lane >> 4;
    const int ln = lane & 15;

    __shared__ ushort_t KT[2][64 * 64];
    __shared__ ushort_t VT[2][64 * 64];

    const ushort_t* kbase = kb + (size_t)bh * SEQ * DH;
    const ushort_t* vbase = vtb + (size_t)bh * DH * SEQ;
    const int b = bh >> 4, h = bh & 15;

    const ushort_t* qrow = qb + ((size_t)bh * SEQ + q0 + wave * 16 + ln) * DH;
    short8 qf0 = *(const short8*)&qrow[lg * 8];
    short8 qf1 = *(const short8*)&qrow[32 + lg * 8];

    f32x4 o[4];
#pragma unroll
    for (int nt = 0; nt < 4; nt++) o[nt] = f32x4{0.f, 0.f, 0.f, 0.f};
    float l = 0.f;                        // per-lane partial for q-row = ln

    // prologue: stage tile t0 into buffer 0
#pragma unroll
    for (int i = 0; i < 2; i++) {
        int f = i * 256 + tid;
        int r = f >> 3, p = f & 7, c = p ^ (r & 7);
        gload16(&kbase[(size_t)(t0 * AKT + r) * DH + c * 8], &KT[0][f * 8]);
        gload16(&vbase[(size_t)r * SEQ + t0 * AKT + c * 8], &VT[0][f * 8]);
    }

    int cur = 0;
    for (int t = t0; t < t1; ++t) {
        __syncthreads();   // staged data for tile t visible

        if (t + 1 < t1) {
            const int nb0 = (t + 1) * AKT;
            const int nxt = cur ^ 1;
#pragma unroll
            for (int i = 0; i < 2; i++) {
                int f = i * 256 + tid;
                int r = f >> 3, p = f & 7, c = p ^ (r & 7);
                gload16(&kbase[(size_t)(nb0 + r) * DH + c * 8], &KT[nxt][f * 8]);
                gload16(&vbase[(size_t)r * SEQ + nb0 + c * 8], &VT[nxt][f * 8]);
            }
        }

        // ---- swapped QK^T: st[kt][r] = S[key=16kt+lg*4+r][q=ln]
        float st[4][4];
        __builtin_amdgcn_s_setprio(1);
#pragma unroll
        for (int kt = 0; kt < 4; kt++) {
            f32x4 acc = f32x4{0.f, 0.f, 0.f, 0.f};
            int krow = kt * 16 + ln;
            short8 b0 = *(const short8*)&KT[cur][krow * 64 + ((lg ^ (krow & 7)) * 8)];
            short8 b1 = *(const short8*)&KT[cur][krow * 64 + (((4 + lg) ^ (krow & 7)) * 8)];
            acc = __builtin_amdgcn_mfma_f32_16x16x32_bf16(b0, qf0, acc, 0, 0, 0);
            acc = __builtin_amdgcn_mfma_f32_16x16x32_bf16(b1, qf1, acc, 0, 0, 0);
#pragma unroll
            for (int r = 0; r < 4; r++) st[kt][r] = acc[r];
        }
        __builtin_amdgcn_s_setprio(0);

        // causal mask only on the diagonal tile (t == qt; never in chunk 0)
        if (t == qt) {
            const int qrel = wave * 16 + ln;
#pragma unroll
            for (int kt = 0; kt < 4; kt++)
#pragma unroll
                for (int r = 0; r < 4; r++)
                    if (kt * 16 + lg * 4 + r > qrel) st[kt][r] = -1e30f;
        }

        // ---- fixed-max softmax: p = exp2(C1*s - M2); P packed in registers
        uint2 pkq[4];
#pragma unroll
        for (int kt = 0; kt < 4; kt++) {
            float pv[4];
#pragma unroll
            for (int r = 0; r < 4; r++) {
                pv[r] = exp2f(fmaf(C1, st[kt][r], -M2));
                l += pv[r];
            }
            pkq[kt].x = cvtpk_bf16(pv[0], pv[1]);
            pkq[kt].y = cvtpk_bf16(pv[2], pv[3]);
        }

        // ---- PV: o[nt] += P(16x16 A-frag, reg) x V^T(8B LDS reads)
        __builtin_amdgcn_s_setprio(1);
#pragma unroll
        for (int nt = 0; nt < 4; nt++) {
            int vrow = nt * 16 + ln;
#pragma unroll
            for (int kt = 0; kt < 4; kt++) {
                int chunk16 = (2 * kt + (lg >> 1)) ^ (vrow & 7);
                uint2 vb = *(const uint2*)&VT[cur][vrow * 64 + chunk16 * 8 + (lg & 1) * 4];
                o[nt] = mfma16_bf16(pkq[kt], vb, o[nt]);
            }
        }
        __builtin_amdgcn_s_setprio(0);

        cur ^= 1;
    }

    // ---- epilogue
    l += __shfl_xor(l, 16);
    l += __shfl_xor(l, 32);

    if (chunk >= 0) {
        // partial: write bf16 o (undivided) + f32 l
        const int pid = ((bh << 4) + (qt - 16)) * 2 + chunk;
        if (lg == 0) lpart[pid * 64 + wave * 16 + ln] = l;
        ushort_t* ob = opart + (size_t)pid * 4096;
#pragma unroll
        for (int r = 0; r < 4; r++) {
            int qrel = wave * 16 + lg * 4 + r;
#pragma unroll
            for (int nt = 0; nt < 4; nt++)
                ob[qrel * 64 + nt * 16 + ln] = f2b(o[nt][r]);
        }
    } else {
        const float rcp = 1.f / l;
#pragma unroll
        for (int r = 0; r < 4; r++) {
            float invl = __shfl(rcp, (lane & 48) | (lg * 4 + r));
            int qg = q0 + wave * 16 + lg * 4 + r;
            ushort_t* op = ctxb + ((size_t)(b * SEQ + qg)) * DM + h * DH;
#pragma unroll
            for (int nt = 0; nt < 4; nt++)
                op[nt * 16 + ln] = f2b(o[nt][r] * invl);
        }
    }
}

// Combine the two partials for qt >= 16: ctx = (o0 + o1) / (l0 + l1).
__global__ __launch_bounds__(256) void attn_reduce(
    const ushort_t* __restrict__ opart, const float* __restrict__ lpart,
    ushort_t* __restrict__ ctxb) {
    const int bh = blockIdx.x;             // 0..31
    const int qt = 16 + blockIdx.y;        // 16..31
    const int tid = threadIdx.x;
    const int q = tid >> 2;                // 0..63
    const int d0 = (tid & 3) * 16;         // 0,16,32,48

    const int pid0 = ((bh << 4) + (qt - 16)) * 2;
    const ushort_t* o0 = opart + (size_t)pid0 * 4096 + q * 64 + d0;
    const ushort_t* o1 = opart + (size_t)(pid0 + 1) * 4096 + q * 64 + d0;
    const float inv = 1.f / (lpart[pid0 * 64 + q] + lpart[(pid0 + 1) * 64 + q]);

    const int b = bh >> 4, h = bh & 15;
    ushort_t* op = ctxb + ((size_t)(b * SEQ + qt * 64 + q)) * DM + h * DH + d0;
#pragma unroll
    for (int half = 0; half < 2; ++half) {
        short8 a = *(const short8*)&o0[half * 8];
        short8 c = *(const short8*)&o1[half * 8];
        short8 r;
#pragma unroll
        for (int j = 0; j < 8; ++j)
            r[j] = (short)f2b((b2f((unsigned short)a[j]) +
                               b2f((unsigned short)c[j])) * inv);
        *(short8*)&op[half * 8] = r;
    }
}

// ---------------- launch ------------------------------------------------------
extern "C" void kernel_launch(void* const* d_in, const int* in_sizes, int n_in,
                              void* d_out, int out_size, void* d_ws, size_t ws_size,
                              hipStream_t stream) {
    const float* x  = (const float*)d_in[0];
    const float* Wq = (const float*)d_in[1];
    const float* bq = (const float*)d_in[2];
    const float* Wk = (const float*)d_in[3];
    const float* bk = (const float*)d_in[4];
    const float* Wv = (const float*)d_in[5];
    const float* bv = (const float*)d_in[6];
    const float* Wo = (const float*)d_in[7];
    const float* bo = (const float*)d_in[8];
    float* out = (float*)d_out;

    constexpr size_t TSZ = (size_t)MROWS * DM;   // 4194304
    constexpr size_t WSZ = (size_t)DM * DM;      // 1048576
    ushort_t* xb  = (ushort_t*)d_ws;
    ushort_t* Wqt = xb + TSZ;
    ushort_t* Wkt = Wqt + WSZ;
    ushort_t* Wvt = Wkt + WSZ;
    ushort_t* Wot = Wvt + WSZ;
    ushort_t* qbp = Wot + WSZ;
    ushort_t* kbp = qbp + TSZ;
    ushort_t* vtp = kbp + TSZ;
    ushort_t* ctxb = vtp + TSZ;

    // attn partials alias regions dead by the time attn runs.
    ushort_t* opart = xb;
    float* lpart = (float*)Wqt;

    conv_all<<<3072, 256, 0, stream>>>(x, xb, Wq, Wk, Wv, Wo, Wqt, Wkt, Wvt, Wot);

    mfma_gemm_qkv<<<dim3(DM / BN, MROWS / BM, 3), 256, 0, stream>>>(
        xb, Wqt, Wkt, Wvt, bq, bk, bv, qbp, kbp, vtp);

    attn_mfma<<<dim3(BATCH * NH, 48), 256, 0, stream>>>(
        qbp, kbp, vtp, ctxb, opart, lpart);
    attn_reduce<<<dim3(BATCH * NH, 16), 256, 0, stream>>>(opart, lpart, ctxb);

    mfma_gemm_out<<<dim3(DM / BN, MROWS / BM), 256, 0, stream>>>(ctxb, Wot, bo, out);
}

// Round 17
// 112.892 us; speedup vs baseline: 1.0716x; 1.0189x over previous
//
#include <hip/hip_runtime.h>
#include <hip/hip_bf16.h>
#include <math.h>

// Problem constants
constexpr int DM = 1024;
constexpr int SEQ = 2048;
constexpr int BATCH = 2;
constexpr int NH = 16;
constexpr int DH = 64;
constexpr int MROWS = BATCH * SEQ;  // 4096
constexpr float SCALE = 0.125f;

typedef __attribute__((ext_vector_type(8))) short short8;
typedef __attribute__((ext_vector_type(4))) float f32x4;
typedef unsigned short ushort_t;

__device__ __forceinline__ unsigned short f2b(float f) {
    __hip_bfloat16 h = __float2bfloat16(f);
    return __builtin_bit_cast(unsigned short, h);
}
__device__ __forceinline__ float b2f(unsigned short u) {
    unsigned int t = ((unsigned int)u) << 16;
    return __builtin_bit_cast(float, t);
}
// v_cvt_pk_bf16_f32: D = {bf16(hi) : bf16(lo)} (no builtin on gfx950 -> asm)
__device__ __forceinline__ unsigned int cvtpk_bf16(float lo, float hi) {
    unsigned int r;
    asm("v_cvt_pk_bf16_f32 %0, %1, %2" : "=v"(r) : "v"(lo), "v"(hi));
    return r;
}
// v_mfma_f32_16x16x16_bf16: A,B = 4 bf16 (2 VGPRs); C/D = 4 f32.
__device__ __forceinline__ f32x4 mfma16_bf16(uint2 a, uint2 b, f32x4 c) {
    asm("v_mfma_f32_16x16x16_bf16 %0, %1, %2, %0"
        : "+v"(c) : "v"(a), "v"(b));
    return c;
}

__device__ __forceinline__ void gload16(const ushort_t* g, ushort_t* l) {
    __builtin_amdgcn_global_load_lds(
        (const __attribute__((address_space(1))) void*)g,
        (__attribute__((address_space(3))) void*)l, 16, 0, 0);
}

// ---------------- merged converter: x -> bf16, W -> transposed bf16 ---------
// blocks [0, 2048): conv_x; blocks [2048, 3072): conv_w (16 x 16 x 4).
__global__ __launch_bounds__(256) void conv_all(
    const float* __restrict__ x, ushort_t* __restrict__ xb,
    const float* __restrict__ Wq, const float* __restrict__ Wk,
    const float* __restrict__ Wv, const float* __restrict__ Wo,
    ushort_t* __restrict__ Wqt, ushort_t* __restrict__ Wkt,
    ushort_t* __restrict__ Wvt, ushort_t* __restrict__ Wot) {
    const int bid = blockIdx.x;
    if (bid < 2048) {
        const size_t idx = (size_t)bid * 256 + threadIdx.x;
        const float4* src = (const float4*)(x + idx * 8);
        float4 a = src[0], b = src[1];
        short8 v;
        v[0] = (short)f2b(a.x); v[1] = (short)f2b(a.y);
        v[2] = (short)f2b(a.z); v[3] = (short)f2b(a.w);
        v[4] = (short)f2b(b.x); v[5] = (short)f2b(b.y);
        v[6] = (short)f2b(b.z); v[7] = (short)f2b(b.w);
        *(short8*)(xb + idx * 8) = v;
        return;
    }
    const int wid = bid - 2048;
    const int z = wid >> 8;
    const int rem = wid & 255;
    const float* W; ushort_t* Wt;
    switch (z) {
        case 0:  W = Wq; Wt = Wqt; break;
        case 1:  W = Wk; Wt = Wkt; break;
        case 2:  W = Wv; Wt = Wvt; break;
        default: W = Wo; Wt = Wot; break;
    }
    __shared__ float L[64][65];
    const int n0 = (rem & 15) * 64, k0 = (rem >> 4) * 64;
    const int t = threadIdx.x;
    const int tr = t >> 4, tc4 = (t & 15) * 4;
#pragma unroll
    for (int i = 0; i < 4; ++i) {
        int kk = tr + i * 16;
        float4 v = *(const float4*)&W[(size_t)(k0 + kk) * DM + n0 + tc4];
        L[kk][tc4 + 0] = v.x; L[kk][tc4 + 1] = v.y;
        L[kk][tc4 + 2] = v.z; L[kk][tc4 + 3] = v.w;
    }
    __syncthreads();
#pragma unroll
    for (int i = 0; i < 4; ++i) {
        int nn = tr + i * 16;
        ushort4 u;
        u.x = f2b(L[tc4 + 0][nn]); u.y = f2b(L[tc4 + 1][nn]);
        u.z = f2b(L[tc4 + 2][nn]); u.w = f2b(L[tc4 + 3][nn]);
        *(ushort4*)&Wt[(size_t)(n0 + nn) * DM + k0 + tc4] = u;
    }
}

// ---------------- MFMA GEMM core: 128x128 tile, BK=32, triple-buffered -------
// Counted-vmcnt pipeline (T4): per K-step wait vmcnt(4) (only the OLDEST
// stage drained), raw s_barrier, issue stage kt+2, then ds_read+MFMA.
// LDS superrow swizzle: buffer = 64 superrows (2 rows) x 8 slots x 16B.
#define BM 128
#define BN 128
#define BKK 32
#define NKT (DM / BKK)   // 32

__device__ __forceinline__ void stage_tile(const ushort_t* __restrict__ A,
                                           const ushort_t* __restrict__ B,
                                           int row0, int col0, int kt,
                                           ushort_t* As, ushort_t* Bs, int tid) {
#pragma unroll
    for (int i = 0; i < 2; ++i) {
        int f = i * 256 + tid;                    // [0,512)
        int sr = f >> 3, p = f & 7;
        int u = p ^ (sr & 7);
        int r = 2 * sr + (u >> 2);                // inverse-swizzled source
        int c = u & 3;
        gload16(&A[(size_t)(row0 + r) * DM + kt * BKK + c * 8], &As[f * 8]);
        gload16(&B[(size_t)(col0 + r) * DM + kt * BKK + c * 8], &Bs[f * 8]);
    }
}

__device__ __forceinline__ void mfma_core(const ushort_t* __restrict__ A,
                                          const ushort_t* __restrict__ B,
                                          int row0, int col0,
                                          ushort_t* smem, f32x4 (&acc)[4][4]) {
    const int tid = threadIdx.x;
    const int wave = tid >> 6, lane = tid & 63;
    const int lg = lane >> 4, ln = lane & 15;
    const int wr = wave >> 1, wc = wave & 1;

    stage_tile(A, B, row0, col0, 0, smem, smem + 4096, tid);
    __builtin_amdgcn_sched_barrier(0);
    stage_tile(A, B, row0, col0, 1, smem + 8192, smem + 12288, tid);

    for (int kt = 0; kt < NKT; ++kt) {
        if (kt + 1 < NKT)
            asm volatile("s_waitcnt vmcnt(4)" ::: "memory");
        else
            asm volatile("s_waitcnt vmcnt(0)" ::: "memory");
        __builtin_amdgcn_s_barrier();

        if (kt + 2 < NKT) {
            ushort_t* An = smem + ((kt + 2) % 3) * 8192;
            stage_tile(A, B, row0, col0, kt + 2, An, An + 4096, tid);
        }

        const ushort_t* As = smem + (kt % 3) * 8192;
        const ushort_t* Bs = As + 4096;
        short8 af[4], bf[4];
#pragma unroll
        for (int mi = 0; mi < 4; ++mi) {
            int r = wr * 64 + mi * 16 + ln;
            int sr = r >> 1;
            int p = (((r & 1) << 2) | lg) ^ (sr & 7);
            af[mi] = *(const short8*)&As[sr * 64 + p * 8];
        }
#pragma unroll
        for (int ni = 0; ni < 4; ++ni) {
            int r = wc * 64 + ni * 16 + ln;
            int sr = r >> 1;
            int p = (((r & 1) << 2) | lg) ^ (sr & 7);
            bf[ni] = *(const short8*)&Bs[sr * 64 + p * 8];
        }
        __builtin_amdgcn_s_setprio(1);
#pragma unroll
        for (int mi = 0; mi < 4; ++mi)
#pragma unroll
            for (int ni = 0; ni < 4; ++ni)
                acc[mi][ni] = __builtin_amdgcn_mfma_f32_16x16x32_bf16(
                    af[mi], bf[ni], acc[mi][ni], 0, 0, 0);
        __builtin_amdgcn_s_setprio(0);
    }
}

// QKV: z=0 -> qb [B,H,S,DH]; z=1 -> kb; z=2 -> vtb [B,H,DH,S]; all bf16 +bias.
// Partial RoPE (rot dim 16) fused into the q/k scatter.
__global__ __launch_bounds__(256) void mfma_gemm_qkv(
    const ushort_t* __restrict__ xb,
    const ushort_t* __restrict__ Wqt, const ushort_t* __restrict__ Wkt,
    const ushort_t* __restrict__ Wvt,
    const float* __restrict__ bq, const float* __restrict__ bk,
    const float* __restrict__ bv,
    ushort_t* __restrict__ qb, ushort_t* __restrict__ kb,
    ushort_t* __restrict__ vtb) {
    const ushort_t* W; const float* bias;
    if (blockIdx.z == 0)      { W = Wqt; bias = bq; }
    else if (blockIdx.z == 1) { W = Wkt; bias = bk; }
    else                      { W = Wvt; bias = bv; }

    const int row0 = blockIdx.y * BM;
    const int col0 = blockIdx.x * BN;
    __shared__ ushort_t smem[24576];   // 48 KB: 3 stage buffers; Cs aliases
    f32x4 acc[4][4] = {};
    mfma_core(xb, W, row0, col0, smem, acc);

    const int tid = threadIdx.x;
    const int wave = tid >> 6, lane = tid & 63;
    const int lg = lane >> 4, ln = lane & 15;
    const int wr = wave >> 1, wc = wave & 1;
    const bool isV = (blockIdx.z == 2);

    __syncthreads();
    ushort_t* Cs = smem;
#pragma unroll
    for (int mi = 0; mi < 4; ++mi)
#pragma unroll
        for (int ni = 0; ni < 4; ++ni)
#pragma unroll
            for (int r = 0; r < 4; ++r) {
                int mrel = wr * 64 + mi * 16 + lg * 4 + r;
                int nrel = wc * 64 + ni * 16 + ln;
                float v = acc[mi][ni][r] + bias[col0 + nrel];
                Cs[isV ? (nrel * 128 + mrel) : (mrel * 128 + nrel)] = f2b(v);
            }
    __syncthreads();

    if (!isV) {
        ushort_t* out = (blockIdx.z == 0) ? qb : kb;
#pragma unroll
        for (int i = 0; i < 8; ++i) {
            int f = i * 256 + tid;
            int rrow = f >> 4, c8 = f & 15;
            int m = row0 + rrow;
            int b = m >> 11, s = m & (SEQ - 1);
            int n = col0 + c8 * 8;
            int h = n >> 6, d = n & 63;
            short8 val;
            if (d < 16) {
                const ushort_t* base = &Cs[rrow * 128 + (c8 & 8) * 8];
                const bool hi = (d >= 8);
#pragma unroll
                for (int j = 0; j < 8; ++j) {
                    float t1 = b2f(base[j]);
                    float t2 = b2f(base[8 + j]);
                    float invf = __expf(-(float)j * 1.1512925465f); // ln(1e4)/8
                    float ang = (float)s * invf;
                    float c_, si_;
                    __sincosf(ang, &si_, &c_);
                    val[j] = (short)f2b(hi ? (t1 * si_ + t2 * c_)
                                           : (t1 * c_ - t2 * si_));
                }
            } else {
                val = *(const short8*)&Cs[rrow * 128 + c8 * 8];
            }
            *(short8*)&out[((size_t)((b * NH + h) * SEQ) + s) * DH + d] = val;
        }
    } else {
#pragma unroll
        for (int i = 0; i < 8; ++i) {
            int f = i * 256 + tid;
            int nrow = f >> 4, c8 = f & 15;
            int n = col0 + nrow;
            int h = n >> 6, d = n & 63;
            int m = row0 + c8 * 8;
            int b = m >> 11, s = m & (SEQ - 1);
            *(short8*)&vtb[((size_t)((b * NH + h) * DH) + d) * SEQ + s] =
                *(const short8*)&Cs[nrow * 128 + c8 * 8];
        }
    }
}

// Output projection: A = ctxb bf16 [M][DM], B = Wot, out fp32 [M][DM] + bo.
__global__ __launch_bounds__(256) void mfma_gemm_out(
    const ushort_t* __restrict__ ctxb, const ushort_t* __restrict__ Wot,
    const float* __restrict__ bo, float* __restrict__ out) {
    const int row0 = blockIdx.y * BM;
    const int col0 = blockIdx.x * BN;
    __shared__ ushort_t smem[24576];
    f32x4 acc[4][4] = {};
    mfma_core(ctxb, Wot, row0, col0, smem, acc);

    const int tid = threadIdx.x;
    const int wave = tid >> 6, lane = tid & 63;
    const int lg = lane >> 4, ln = lane & 15;
    const int wr = wave >> 1, wc = wave & 1;
#pragma unroll
    for (int mi = 0; mi < 4; ++mi)
#pragma unroll
        for (int ni = 0; ni < 4; ++ni)
#pragma unroll
            for (int r = 0; r < 4; ++r) {
                int m = row0 + wr * 64 + mi * 16 + lg * 4 + r;
                int n = col0 + wc * 64 + ni * 16 + ln;
                out[(size_t)m * DM + n] = acc[mi][ni][r] + bo[n];
            }
}

// ---------------- Causal flash attention, k-split, SINGLE-buffered LDS ------
// 16 KB LDS/block -> residency cap 8 blocks/CU (was 5 at 32 KB); the whole
// 1536-block grid (6/CU) is co-resident, so inter-block TLP hides the
// exposed per-step staging latency (stage -> sync -> compute -> sync).
// Fixed-max softmax => k-split partials additive. Slots per bh (y):
//   y in [0,16):  qt = 16+y,  tiles [0,16)      -> partial chunk 0
//   y in [16,32): qt = 47-y,  tiles [16,qt+1)   -> partial chunk 1
//   y in [32,48): qt = 47-y,  tiles [0,qt+1)    -> direct ctx write
#define AQT 64
#define AKT 64
#define NQT (SEQ / AQT)   // 32

__global__ __launch_bounds__(256) void attn_mfma(
    const ushort_t* __restrict__ qb, const ushort_t* __restrict__ kb,
    const ushort_t* __restrict__ vtb, ushort_t* __restrict__ ctxb,
    ushort_t* __restrict__ opart, float* __restrict__ lpart) {
    constexpr float C1 = 0.18033688f;        // SCALE * log2(e)
    constexpr float M2 = 1.44269504f;        // C1 * 8 (score bound 8 sigma)
    const int bh = blockIdx.x;
    const int y = blockIdx.y;

    int qt, t0, t1, chunk;
    if (y < 16)      { qt = 16 + y;  t0 = 0;  t1 = 16;     chunk = 0; }
    else if (y < 32) { qt = 47 - y;  t0 = 16; t1 = qt + 1; chunk = 1; }
    else             { qt = 47 - y;  t0 = 0;  t1 = qt + 1; chunk = -1; }
    const int q0 = qt * AQT;

    const int tid = threadIdx.x;
    const int wave = tid >> 6;
    const int lane = tid & 63;
    const int lg = lane >> 4;
    const int ln = lane & 15;

    __shared__ ushort_t KT[64 * 64];   // single buffer: 8 KB
    __shared__ ushort_t VT[64 * 64];   // single buffer: 8 KB

    const ushort_t* kbase = kb + (size_t)bh * SEQ * DH;
    const ushort_t* vbase = vtb + (size_t)bh * DH * SEQ;
    const int b = bh >> 4, h = bh & 15;

    const ushort_t* qrow = qb + ((size_t)bh * SEQ + q0 + wave * 16 + ln) * DH;
    short8 qf0 = *(const short8*)&qrow[lg * 8];
    short8 qf1 = *(const short8*)&qrow[32 + lg * 8];

    f32x4 o[4];
#pragma unroll
    for (int nt = 0; nt < 4; nt++) o[nt] = f32x4{0.f, 0.f, 0.f, 0.f};
    float l = 0.f;                        // per-lane partial for q-row = ln

    // prologue: stage tile t0
#pragma unroll
    for (int i = 0; i < 2; i++) {
        int f = i * 256 + tid;
        int r = f >> 3, p = f & 7, c = p ^ (r & 7);
        gload16(&kbase[(size_t)(t0 * AKT + r) * DH + c * 8], &KT[f * 8]);
        gload16(&vbase[(size_t)r * SEQ + t0 * AKT + c * 8], &VT[f * 8]);
    }

    for (int t = t0; t < t1; ++t) {
        __syncthreads();   // staging for tile t drained (vmcnt 0) & visible

        // ---- swapped QK^T: st[kt][r] = S[key=16kt+lg*4+r][q=ln]
        float st[4][4];
        __builtin_amdgcn_s_setprio(1);
#pragma unroll
        for (int kt = 0; kt < 4; kt++) {
            f32x4 acc = f32x4{0.f, 0.f, 0.f, 0.f};
            int krow = kt * 16 + ln;
            short8 b0 = *(const short8*)&KT[krow * 64 + ((lg ^ (krow & 7)) * 8)];
            short8 b1 = *(const short8*)&KT[krow * 64 + (((4 + lg) ^ (krow & 7)) * 8)];
            acc = __builtin_amdgcn_mfma_f32_16x16x32_bf16(b0, qf0, acc, 0, 0, 0);
            acc = __builtin_amdgcn_mfma_f32_16x16x32_bf16(b1, qf1, acc, 0, 0, 0);
#pragma unroll
            for (int r = 0; r < 4; r++) st[kt][r] = acc[r];
        }
        __builtin_amdgcn_s_setprio(0);

        // causal mask only on the diagonal tile (t == qt; never in chunk 0)
        if (t == qt) {
            const int qrel = wave * 16 + ln;
#pragma unroll
            for (int kt = 0; kt < 4; kt++)
#pragma unroll
                for (int r = 0; r < 4; r++)
                    if (kt * 16 + lg * 4 + r > qrel) st[kt][r] = -1e30f;
        }

        // ---- fixed-max softmax: p = exp2(C1*s - M2); P packed in registers
        uint2 pkq[4];
#pragma unroll
        for (int kt = 0; kt < 4; kt++) {
            float pv[4];
#pragma unroll
            for (int r = 0; r < 4; r++) {
                pv[r] = exp2f(fmaf(C1, st[kt][r], -M2));
                l += pv[r];
            }
            pkq[kt].x = cvtpk_bf16(pv[0], pv[1]);
            pkq[kt].y = cvtpk_bf16(pv[2], pv[3]);
        }

        // ---- PV: o[nt] += P(16x16 A-frag, reg) x V^T(8B LDS reads)
        __builtin_amdgcn_s_setprio(1);
#pragma unroll
        for (int nt = 0; nt < 4; nt++) {
            int vrow = nt * 16 + ln;
#pragma unroll
            for (int kt = 0; kt < 4; kt++) {
                int chunk16 = (2 * kt + (lg >> 1)) ^ (vrow & 7);
                uint2 vb = *(const uint2*)&VT[vrow * 64 + chunk16 * 8 + (lg & 1) * 4];
                o[nt] = mfma16_bf16(pkq[kt], vb, o[nt]);
            }
        }
        __builtin_amdgcn_s_setprio(0);

        // stage tile t+1 (after all waves are done reading this tile)
        if (t + 1 < t1) {
            __syncthreads();
            const int nb0 = (t + 1) * AKT;
#pragma unroll
            for (int i = 0; i < 2; i++) {
                int f = i * 256 + tid;
                int r = f >> 3, p = f & 7, c = p ^ (r & 7);
                gload16(&kbase[(size_t)(nb0 + r) * DH + c * 8], &KT[f * 8]);
                gload16(&vbase[(size_t)r * SEQ + nb0 + c * 8], &VT[f * 8]);
            }
        }
    }

    // ---- epilogue
    l += __shfl_xor(l, 16);
    l += __shfl_xor(l, 32);

    if (chunk >= 0) {
        // partial: write bf16 o (undivided) + f32 l
        const int pid = ((bh << 4) + (qt - 16)) * 2 + chunk;
        if (lg == 0) lpart[pid * 64 + wave * 16 + ln] = l;
        ushort_t* ob = opart + (size_t)pid * 4096;
#pragma unroll
        for (int r = 0; r < 4; r++) {
            int qrel = wave * 16 + lg * 4 + r;
#pragma unroll
            for (int nt = 0; nt < 4; nt++)
                ob[qrel * 64 + nt * 16 + ln] = f2b(o[nt][r]);
        }
    } else {
        const float rcp = 1.f / l;
#pragma unroll
        for (int r = 0; r < 4; r++) {
            float invl = __shfl(rcp, (lane & 48) | (lg * 4 + r));
            int qg = q0 + wave * 16 + lg * 4 + r;
            ushort_t* op = ctxb + ((size_t)(b * SEQ + qg)) * DM + h * DH;
#pragma unroll
            for (int nt = 0; nt < 4; nt++)
                op[nt * 16 + ln] = f2b(o[nt][r] * invl);
        }
    }
}

// Combine the two partials for qt >= 16: ctx = (o0 + o1) / (l0 + l1).
__global__ __launch_bounds__(256) void attn_reduce(
    const ushort_t* __restrict__ opart, const float* __restrict__ lpart,
    ushort_t* __restrict__ ctxb) {
    const int bh = blockIdx.x;             // 0..31
    const int qt = 16 + blockIdx.y;        // 16..31
    const int tid = threadIdx.x;
    const int q = tid >> 2;                // 0..63
    const int d0 = (tid & 3) * 16;         // 0,16,32,48

    const int pid0 = ((bh << 4) + (qt - 16)) * 2;
    const ushort_t* o0 = opart + (size_t)pid0 * 4096 + q * 64 + d0;
    const ushort_t* o1 = opart + (size_t)(pid0 + 1) * 4096 + q * 64 + d0;
    const float inv = 1.f / (lpart[pid0 * 64 + q] + lpart[(pid0 + 1) * 64 + q]);

    const int b = bh >> 4, h = bh & 15;
    ushort_t* op = ctxb + ((size_t)(b * SEQ + qt * 64 + q)) * DM + h * DH + d0;
#pragma unroll
    for (int half = 0; half < 2; ++half) {
        short8 a = *(const short8*)&o0[half * 8];
        short8 c = *(const short8*)&o1[half * 8];
        short8 r;
#pragma unroll
        for (int j = 0; j < 8; ++j)
            r[j] = (short)f2b((b2f((unsigned short)a[j]) +
                               b2f((unsigned short)c[j])) * inv);
        *(short8*)&op[half * 8] = r;
    }
}

// ---------------- launch ------------------------------------------------------
extern "C" void kernel_launch(void* const* d_in, const int* in_sizes, int n_in,
                              void* d_out, int out_size, void* d_ws, size_t ws_size,
                              hipStream_t stream) {
    const float* x  = (const float*)d_in[0];
    const float* Wq = (const float*)d_in[1];
    const float* bq = (const float*)d_in[2];
    const float* Wk = (const float*)d_in[3];
    const float* bk = (const float*)d_in[4];
    const float* Wv = (const float*)d_in[5];
    const float* bv = (const float*)d_in[6];
    const float* Wo = (const float*)d_in[7];
    const float* bo = (const float*)d_in[8];
    float* out = (float*)d_out;

    constexpr size_t TSZ = (size_t)MROWS * DM;   // 4194304
    constexpr size_t WSZ = (size_t)DM * DM;      // 1048576
    ushort_t* xb  = (ushort_t*)d_ws;
    ushort_t* Wqt = xb + TSZ;
    ushort_t* Wkt = Wqt + WSZ;
    ushort_t* Wvt = Wkt + WSZ;
    ushort_t* Wot = Wvt + WSZ;
    ushort_t* qbp = Wot + WSZ;
    ushort_t* kbp = qbp + TSZ;
    ushort_t* vtp = kbp + TSZ;
    ushort_t* ctxb = vtp + TSZ;

    // attn partials alias regions dead by the time attn runs.
    ushort_t* opart = xb;
    float* lpart = (float*)Wqt;

    conv_all<<<3072, 256, 0, stream>>>(x, xb, Wq, Wk, Wv, Wo, Wqt, Wkt, Wvt, Wot);

    mfma_gemm_qkv<<<dim3(DM / BN, MROWS / BM, 3), 256, 0, stream>>>(
        xb, Wqt, Wkt, Wvt, bq, bk, bv, qbp, kbp, vtp);

    attn_mfma<<<dim3(BATCH * NH, 48), 256, 0, stream>>>(
        qbp, kbp, vtp, ctxb, opart, lpart);
    attn_reduce<<<dim3(BATCH * NH, 16), 256, 0, stream>>>(opart, lpart, ctxb);

    mfma_gemm_out<<<dim3(DM / BN, MROWS / BM), 256, 0, stream>>>(ctxb, Wot, bo, out);
}

// Round 18
// 111.770 us; speedup vs baseline: 1.0824x; 1.0100x over previous
//
#include <hip/hip_runtime.h>
#include <hip/hip_bf16.h>
#include <math.h>

// Problem constants
constexpr int DM = 1024;
constexpr int SEQ = 2048;
constexpr int BATCH = 2;
constexpr int NH = 16;
constexpr int DH = 64;
constexpr int MROWS = BATCH * SEQ;  // 4096
constexpr float SCALE = 0.125f;

typedef __attribute__((ext_vector_type(8))) short short8;
typedef __attribute__((ext_vector_type(4))) float f32x4;
typedef unsigned short ushort_t;

__device__ __forceinline__ unsigned short f2b(float f) {
    __hip_bfloat16 h = __float2bfloat16(f);
    return __builtin_bit_cast(unsigned short, h);
}
__device__ __forceinline__ float b2f(unsigned short u) {
    unsigned int t = ((unsigned int)u) << 16;
    return __builtin_bit_cast(float, t);
}
// v_cvt_pk_bf16_f32: D = {bf16(hi) : bf16(lo)} (no builtin on gfx950 -> asm)
__device__ __forceinline__ unsigned int cvtpk_bf16(float lo, float hi) {
    unsigned int r;
    asm("v_cvt_pk_bf16_f32 %0, %1, %2" : "=v"(r) : "v"(lo), "v"(hi));
    return r;
}
// v_mfma_f32_16x16x16_bf16: A,B = 4 bf16 (2 VGPRs); C/D = 4 f32.
__device__ __forceinline__ f32x4 mfma16_bf16(uint2 a, uint2 b, f32x4 c) {
    asm("v_mfma_f32_16x16x16_bf16 %0, %1, %2, %0"
        : "+v"(c) : "v"(a), "v"(b));
    return c;
}

__device__ __forceinline__ void gload16(const ushort_t* g, ushort_t* l) {
    __builtin_amdgcn_global_load_lds(
        (const __attribute__((address_space(1))) void*)g,
        (__attribute__((address_space(3))) void*)l, 16, 0, 0);
}

// ---------------- merged converter: x -> bf16, W -> transposed bf16 ---------
// blocks [0, 2048): conv_x; blocks [2048, 3072): conv_w (16 x 16 x 4).
__global__ __launch_bounds__(256) void conv_all(
    const float* __restrict__ x, ushort_t* __restrict__ xb,
    const float* __restrict__ Wq, const float* __restrict__ Wk,
    const float* __restrict__ Wv, const float* __restrict__ Wo,
    ushort_t* __restrict__ Wqt, ushort_t* __restrict__ Wkt,
    ushort_t* __restrict__ Wvt, ushort_t* __restrict__ Wot) {
    const int bid = blockIdx.x;
    if (bid < 2048) {
        const size_t idx = (size_t)bid * 256 + threadIdx.x;
        const float4* src = (const float4*)(x + idx * 8);
        float4 a = src[0], b = src[1];
        short8 v;
        v[0] = (short)f2b(a.x); v[1] = (short)f2b(a.y);
        v[2] = (short)f2b(a.z); v[3] = (short)f2b(a.w);
        v[4] = (short)f2b(b.x); v[5] = (short)f2b(b.y);
        v[6] = (short)f2b(b.z); v[7] = (short)f2b(b.w);
        *(short8*)(xb + idx * 8) = v;
        return;
    }
    const int wid = bid - 2048;
    const int z = wid >> 8;
    const int rem = wid & 255;
    const float* W; ushort_t* Wt;
    switch (z) {
        case 0:  W = Wq; Wt = Wqt; break;
        case 1:  W = Wk; Wt = Wkt; break;
        case 2:  W = Wv; Wt = Wvt; break;
        default: W = Wo; Wt = Wot; break;
    }
    __shared__ float L[64][65];
    const int n0 = (rem & 15) * 64, k0 = (rem >> 4) * 64;
    const int t = threadIdx.x;
    const int tr = t >> 4, tc4 = (t & 15) * 4;
#pragma unroll
    for (int i = 0; i < 4; ++i) {
        int kk = tr + i * 16;
        float4 v = *(const float4*)&W[(size_t)(k0 + kk) * DM + n0 + tc4];
        L[kk][tc4 + 0] = v.x; L[kk][tc4 + 1] = v.y;
        L[kk][tc4 + 2] = v.z; L[kk][tc4 + 3] = v.w;
    }
    __syncthreads();
#pragma unroll
    for (int i = 0; i < 4; ++i) {
        int nn = tr + i * 16;
        ushort4 u;
        u.x = f2b(L[tc4 + 0][nn]); u.y = f2b(L[tc4 + 1][nn]);
        u.z = f2b(L[tc4 + 2][nn]); u.w = f2b(L[tc4 + 3][nn]);
        *(ushort4*)&Wt[(size_t)(n0 + nn) * DM + k0 + tc4] = u;
    }
}

// ---------------- MFMA GEMM core: 128x128 tile, BK=32, triple-buffered -------
// Counted-vmcnt pipeline (T4): per K-step wait vmcnt(4) (only the OLDEST
// stage drained), raw s_barrier, issue stage kt+2, then ds_read+MFMA.
// LDS superrow swizzle: buffer = 64 superrows (2 rows) x 8 slots x 16B.
#define BM 128
#define BN 128
#define BKK 32
#define NKT (DM / BKK)   // 32

__device__ __forceinline__ void stage_tile(const ushort_t* __restrict__ A,
                                           const ushort_t* __restrict__ B,
                                           int row0, int col0, int kt,
                                           ushort_t* As, ushort_t* Bs, int tid) {
#pragma unroll
    for (int i = 0; i < 2; ++i) {
        int f = i * 256 + tid;                    // [0,512)
        int sr = f >> 3, p = f & 7;
        int u = p ^ (sr & 7);
        int r = 2 * sr + (u >> 2);                // inverse-swizzled source
        int c = u & 3;
        gload16(&A[(size_t)(row0 + r) * DM + kt * BKK + c * 8], &As[f * 8]);
        gload16(&B[(size_t)(col0 + r) * DM + kt * BKK + c * 8], &Bs[f * 8]);
    }
}

__device__ __forceinline__ void mfma_core(const ushort_t* __restrict__ A,
                                          const ushort_t* __restrict__ B,
                                          int row0, int col0,
                                          ushort_t* smem, f32x4 (&acc)[4][4]) {
    const int tid = threadIdx.x;
    const int wave = tid >> 6, lane = tid & 63;
    const int lg = lane >> 4, ln = lane & 15;
    const int wr = wave >> 1, wc = wave & 1;

    stage_tile(A, B, row0, col0, 0, smem, smem + 4096, tid);
    __builtin_amdgcn_sched_barrier(0);
    stage_tile(A, B, row0, col0, 1, smem + 8192, smem + 12288, tid);

    for (int kt = 0; kt < NKT; ++kt) {
        if (kt + 1 < NKT)
            asm volatile("s_waitcnt vmcnt(4)" ::: "memory");
        else
            asm volatile("s_waitcnt vmcnt(0)" ::: "memory");
        __builtin_amdgcn_s_barrier();

        if (kt + 2 < NKT) {
            ushort_t* An = smem + ((kt + 2) % 3) * 8192;
            stage_tile(A, B, row0, col0, kt + 2, An, An + 4096, tid);
        }

        const ushort_t* As = smem + (kt % 3) * 8192;
        const ushort_t* Bs = As + 4096;
        short8 af[4], bf[4];
#pragma unroll
        for (int mi = 0; mi < 4; ++mi) {
            int r = wr * 64 + mi * 16 + ln;
            int sr = r >> 1;
            int p = (((r & 1) << 2) | lg) ^ (sr & 7);
            af[mi] = *(const short8*)&As[sr * 64 + p * 8];
        }
#pragma unroll
        for (int ni = 0; ni < 4; ++ni) {
            int r = wc * 64 + ni * 16 + ln;
            int sr = r >> 1;
            int p = (((r & 1) << 2) | lg) ^ (sr & 7);
            bf[ni] = *(const short8*)&Bs[sr * 64 + p * 8];
        }
        __builtin_amdgcn_s_setprio(1);
#pragma unroll
        for (int mi = 0; mi < 4; ++mi)
#pragma unroll
            for (int ni = 0; ni < 4; ++ni)
                acc[mi][ni] = __builtin_amdgcn_mfma_f32_16x16x32_bf16(
                    af[mi], bf[ni], acc[mi][ni], 0, 0, 0);
        __builtin_amdgcn_s_setprio(0);
    }
}

// QKV: z=0 -> qb [B,H,S,DH]; z=1 -> kb; z=2 -> vtb [B,H,DH,S]; all bf16 +bias.
// Partial RoPE (rot dim 16) fused into the q/k scatter.
__global__ __launch_bounds__(256) void mfma_gemm_qkv(
    const ushort_t* __restrict__ xb,
    const ushort_t* __restrict__ Wqt, const ushort_t* __restrict__ Wkt,
    const ushort_t* __restrict__ Wvt,
    const float* __restrict__ bq, const float* __restrict__ bk,
    const float* __restrict__ bv,
    ushort_t* __restrict__ qb, ushort_t* __restrict__ kb,
    ushort_t* __restrict__ vtb) {
    const ushort_t* W; const float* bias;
    if (blockIdx.z == 0)      { W = Wqt; bias = bq; }
    else if (blockIdx.z == 1) { W = Wkt; bias = bk; }
    else                      { W = Wvt; bias = bv; }

    const int row0 = blockIdx.y * BM;
    const int col0 = blockIdx.x * BN;
    __shared__ ushort_t smem[24576];   // 48 KB: 3 stage buffers; Cs aliases
    f32x4 acc[4][4] = {};
    mfma_core(xb, W, row0, col0, smem, acc);

    const int tid = threadIdx.x;
    const int wave = tid >> 6, lane = tid & 63;
    const int lg = lane >> 4, ln = lane & 15;
    const int wr = wave >> 1, wc = wave & 1;
    const bool isV = (blockIdx.z == 2);

    __syncthreads();
    ushort_t* Cs = smem;
#pragma unroll
    for (int mi = 0; mi < 4; ++mi)
#pragma unroll
        for (int ni = 0; ni < 4; ++ni)
#pragma unroll
            for (int r = 0; r < 4; ++r) {
                int mrel = wr * 64 + mi * 16 + lg * 4 + r;
                int nrel = wc * 64 + ni * 16 + ln;
                float v = acc[mi][ni][r] + bias[col0 + nrel];
                Cs[isV ? (nrel * 128 + mrel) : (mrel * 128 + nrel)] = f2b(v);
            }
    __syncthreads();

    if (!isV) {
        ushort_t* out = (blockIdx.z == 0) ? qb : kb;
#pragma unroll
        for (int i = 0; i < 8; ++i) {
            int f = i * 256 + tid;
            int rrow = f >> 4, c8 = f & 15;
            int m = row0 + rrow;
            int b = m >> 11, s = m & (SEQ - 1);
            int n = col0 + c8 * 8;
            int h = n >> 6, d = n & 63;
            short8 val;
            if (d < 16) {
                const ushort_t* base = &Cs[rrow * 128 + (c8 & 8) * 8];
                const bool hi = (d >= 8);
#pragma unroll
                for (int j = 0; j < 8; ++j) {
                    float t1 = b2f(base[j]);
                    float t2 = b2f(base[8 + j]);
                    float invf = __expf(-(float)j * 1.1512925465f); // ln(1e4)/8
                    float ang = (float)s * invf;
                    float c_, si_;
                    __sincosf(ang, &si_, &c_);
                    val[j] = (short)f2b(hi ? (t1 * si_ + t2 * c_)
                                           : (t1 * c_ - t2 * si_));
                }
            } else {
                val = *(const short8*)&Cs[rrow * 128 + c8 * 8];
            }
            *(short8*)&out[((size_t)((b * NH + h) * SEQ) + s) * DH + d] = val;
        }
    } else {
#pragma unroll
        for (int i = 0; i < 8; ++i) {
            int f = i * 256 + tid;
            int nrow = f >> 4, c8 = f & 15;
            int n = col0 + nrow;
            int h = n >> 6, d = n & 63;
            int m = row0 + c8 * 8;
            int b = m >> 11, s = m & (SEQ - 1);
            *(short8*)&vtb[((size_t)((b * NH + h) * DH) + d) * SEQ + s] =
                *(const short8*)&Cs[nrow * 128 + c8 * 8];
        }
    }
}

// Output projection: A = ctxb bf16 [M][DM], B = Wot, out fp32 [M][DM] + bo.
__global__ __launch_bounds__(256) void mfma_gemm_out(
    const ushort_t* __restrict__ ctxb, const ushort_t* __restrict__ Wot,
    const float* __restrict__ bo, float* __restrict__ out) {
    const int row0 = blockIdx.y * BM;
    const int col0 = blockIdx.x * BN;
    __shared__ ushort_t smem[24576];
    f32x4 acc[4][4] = {};
    mfma_core(ctxb, Wot, row0, col0, smem, acc);

    const int tid = threadIdx.x;
    const int wave = tid >> 6, lane = tid & 63;
    const int lg = lane >> 4, ln = lane & 15;
    const int wr = wave >> 1, wc = wave & 1;
#pragma unroll
    for (int mi = 0; mi < 4; ++mi)
#pragma unroll
        for (int ni = 0; ni < 4; ++ni)
#pragma unroll
            for (int r = 0; r < 4; ++r) {
                int m = row0 + wr * 64 + mi * 16 + lg * 4 + r;
                int n = col0 + wc * 64 + ni * 16 + ln;
                out[(size_t)m * DM + n] = acc[mi][ni][r] + bo[n];
            }
}

// ---------------- Causal flash attention, k-split, K-single / V-double ------
// 24 KB LDS/block -> cap 6 blocks/CU = grid's exact 6/CU (R17 residency).
// Per step: sync -> QK^T(KT) -> sync(KT free) -> issue K(t+1)->KT and
// V(t+1)->VT[nxt] -> softmax+PV(VT[cur]) -> loop-top sync drains. The
// softmax+PV phase covers most of the staging latency (T14 issue-early).
// Fixed-max softmax => k-split partials additive. Slots per bh (y):
//   y in [0,16):  qt = 16+y,  tiles [0,16)      -> partial chunk 0
//   y in [16,32): qt = 47-y,  tiles [16,qt+1)   -> partial chunk 1
//   y in [32,48): qt = 47-y,  tiles [0,qt+1)    -> direct ctx write
#define AQT 64
#define AKT 64
#define NQT (SEQ / AQT)   // 32

__global__ __launch_bounds__(256) void attn_mfma(
    const ushort_t* __restrict__ qb, const ushort_t* __restrict__ kb,
    const ushort_t* __restrict__ vtb, ushort_t* __restrict__ ctxb,
    ushort_t* __restrict__ opart, float* __restrict__ lpart) {
    constexpr float C1 = 0.18033688f;        // SCALE * log2(e)
    constexpr float M2 = 1.44269504f;        // C1 * 8 (score bound 8 sigma)
    const int bh = blockIdx.x;
    const int y = blockIdx.y;

    int qt, t0, t1, chunk;
    if (y < 16)      { qt = 16 + y;  t0 = 0;  t1 = 16;     chunk = 0; }
    else if (y < 32) { qt = 47 - y;  t0 = 16; t1 = qt + 1; chunk = 1; }
    else             { qt = 47 - y;  t0 = 0;  t1 = qt + 1; chunk = -1; }
    const int q0 = qt * AQT;

    const int tid = threadIdx.x;
    const int wave = tid >> 6;
    const int lane = tid & 63;
    const int lg = lane >> 4;
    const int ln = lane & 15;

    __shared__ ushort_t KT[64 * 64];      // K single buffer: 8 KB
    __shared__ ushort_t VT[2][64 * 64];   // V double buffer: 16 KB

    const ushort_t* kbase = kb + (size_t)bh * SEQ * DH;
    const ushort_t* vbase = vtb + (size_t)bh * DH * SEQ;
    const int b = bh >> 4, h = bh & 15;

    const ushort_t* qrow = qb + ((size_t)bh * SEQ + q0 + wave * 16 + ln) * DH;
    short8 qf0 = *(const short8*)&qrow[lg * 8];
    short8 qf1 = *(const short8*)&qrow[32 + lg * 8];

    f32x4 o[4];
#pragma unroll
    for (int nt = 0; nt < 4; nt++) o[nt] = f32x4{0.f, 0.f, 0.f, 0.f};
    float l = 0.f;                        // per-lane partial for q-row = ln

    // prologue: stage tile t0 (K->KT, V->VT[0])
#pragma unroll
    for (int i = 0; i < 2; i++) {
        int f = i * 256 + tid;
        int r = f >> 3, p = f & 7, c = p ^ (r & 7);
        gload16(&kbase[(size_t)(t0 * AKT + r) * DH + c * 8], &KT[f * 8]);
        gload16(&vbase[(size_t)r * SEQ + t0 * AKT + c * 8], &VT[0][f * 8]);
    }

    int cur = 0;
    for (int t = t0; t < t1; ++t) {
        __syncthreads();   // staging for tile t drained & visible

        // ---- swapped QK^T: st[kt][r] = S[key=16kt+lg*4+r][q=ln]
        float st[4][4];
        __builtin_amdgcn_s_setprio(1);
#pragma unroll
        for (int kt = 0; kt < 4; kt++) {
            f32x4 acc = f32x4{0.f, 0.f, 0.f, 0.f};
            int krow = kt * 16 + ln;
            short8 b0 = *(const short8*)&KT[krow * 64 + ((lg ^ (krow & 7)) * 8)];
            short8 b1 = *(const short8*)&KT[krow * 64 + (((4 + lg) ^ (krow & 7)) * 8)];
            acc = __builtin_amdgcn_mfma_f32_16x16x32_bf16(b0, qf0, acc, 0, 0, 0);
            acc = __builtin_amdgcn_mfma_f32_16x16x32_bf16(b1, qf1, acc, 0, 0, 0);
#pragma unroll
            for (int r = 0; r < 4; r++) st[kt][r] = acc[r];
        }
        __builtin_amdgcn_s_setprio(0);

        __syncthreads();   // all waves done reading KT -> safe to overwrite

        // issue next tile's staging NOW; flies under softmax + PV
        if (t + 1 < t1) {
            const int nb0 = (t + 1) * AKT;
            const int nxt = cur ^ 1;
#pragma unroll
            for (int i = 0; i < 2; i++) {
                int f = i * 256 + tid;
                int r = f >> 3, p = f & 7, c = p ^ (r & 7);
                gload16(&kbase[(size_t)(nb0 + r) * DH + c * 8], &KT[f * 8]);
                gload16(&vbase[(size_t)r * SEQ + nb0 + c * 8], &VT[nxt][f * 8]);
            }
        }

        // causal mask only on the diagonal tile (t == qt; never in chunk 0)
        if (t == qt) {
            const int qrel = wave * 16 + ln;
#pragma unroll
            for (int kt = 0; kt < 4; kt++)
#pragma unroll
                for (int r = 0; r < 4; r++)
                    if (kt * 16 + lg * 4 + r > qrel) st[kt][r] = -1e30f;
        }

        // ---- fixed-max softmax: p = exp2(C1*s - M2); P packed in registers
        uint2 pkq[4];
#pragma unroll
        for (int kt = 0; kt < 4; kt++) {
            float pv[4];
#pragma unroll
            for (int r = 0; r < 4; r++) {
                pv[r] = exp2f(fmaf(C1, st[kt][r], -M2));
                l += pv[r];
            }
            pkq[kt].x = cvtpk_bf16(pv[0], pv[1]);
            pkq[kt].y = cvtpk_bf16(pv[2], pv[3]);
        }

        // ---- PV: o[nt] += P(16x16 A-frag, reg) x V^T(8B LDS reads, cur buf)
        __builtin_amdgcn_s_setprio(1);
#pragma unroll
        for (int nt = 0; nt < 4; nt++) {
            int vrow = nt * 16 + ln;
#pragma unroll
            for (int kt = 0; kt < 4; kt++) {
                int chunk16 = (2 * kt + (lg >> 1)) ^ (vrow & 7);
                uint2 vb = *(const uint2*)&VT[cur][vrow * 64 + chunk16 * 8 + (lg & 1) * 4];
                o[nt] = mfma16_bf16(pkq[kt], vb, o[nt]);
            }
        }
        __builtin_amdgcn_s_setprio(0);

        cur ^= 1;
    }

    // ---- epilogue
    l += __shfl_xor(l, 16);
    l += __shfl_xor(l, 32);

    if (chunk >= 0) {
        // partial: write bf16 o (undivided) + f32 l
        const int pid = ((bh << 4) + (qt - 16)) * 2 + chunk;
        if (lg == 0) lpart[pid * 64 + wave * 16 + ln] = l;
        ushort_t* ob = opart + (size_t)pid * 4096;
#pragma unroll
        for (int r = 0; r < 4; r++) {
            int qrel = wave * 16 + lg * 4 + r;
#pragma unroll
            for (int nt = 0; nt < 4; nt++)
                ob[qrel * 64 + nt * 16 + ln] = f2b(o[nt][r]);
        }
    } else {
        const float rcp = 1.f / l;
#pragma unroll
        for (int r = 0; r < 4; r++) {
            float invl = __shfl(rcp, (lane & 48) | (lg * 4 + r));
            int qg = q0 + wave * 16 + lg * 4 + r;
            ushort_t* op = ctxb + ((size_t)(b * SEQ + qg)) * DM + h * DH;
#pragma unroll
            for (int nt = 0; nt < 4; nt++)
                op[nt * 16 + ln] = f2b(o[nt][r] * invl);
        }
    }
}

// Combine the two partials for qt >= 16: ctx = (o0 + o1) / (l0 + l1).
__global__ __launch_bounds__(256) void attn_reduce(
    const ushort_t* __restrict__ opart, const float* __restrict__ lpart,
    ushort_t* __restrict__ ctxb) {
    const int bh = blockIdx.x;             // 0..31
    const int qt = 16 + blockIdx.y;        // 16..31
    const int tid = threadIdx.x;
    const int q = tid >> 2;                // 0..63
    const int d0 = (tid & 3) * 16;         // 0,16,32,48

    const int pid0 = ((bh << 4) + (qt - 16)) * 2;
    const ushort_t* o0 = opart + (size_t)pid0 * 4096 + q * 64 + d0;
    const ushort_t* o1 = opart + (size_t)(pid0 + 1) * 4096 + q * 64 + d0;
    const float inv = 1.f / (lpart[pid0 * 64 + q] + lpart[(pid0 + 1) * 64 + q]);

    const int b = bh >> 4, h = bh & 15;
    ushort_t* op = ctxb + ((size_t)(b * SEQ + qt * 64 + q)) * DM + h * DH + d0;
#pragma unroll
    for (int half = 0; half < 2; ++half) {
        short8 a = *(const short8*)&o0[half * 8];
        short8 c = *(const short8*)&o1[half * 8];
        short8 r;
#pragma unroll
        for (int j = 0; j < 8; ++j)
            r[j] = (short)f2b((b2f((unsigned short)a[j]) +
                               b2f((unsigned short)c[j])) * inv);
        *(short8*)&op[half * 8] = r;
    }
}

// ---------------- launch ------------------------------------------------------
extern "C" void kernel_launch(void* const* d_in, const int* in_sizes, int n_in,
                              void* d_out, int out_size, void* d_ws, size_t ws_size,
                              hipStream_t stream) {
    const float* x  = (const float*)d_in[0];
    const float* Wq = (const float*)d_in[1];
    const float* bq = (const float*)d_in[2];
    const float* Wk = (const float*)d_in[3];
    const float* bk = (const float*)d_in[4];
    const float* Wv = (const float*)d_in[5];
    const float* bv = (const float*)d_in[6];
    const float* Wo = (const float*)d_in[7];
    const float* bo = (const float*)d_in[8];
    float* out = (float*)d_out;

    constexpr size_t TSZ = (size_t)MROWS * DM;   // 4194304
    constexpr size_t WSZ = (size_t)DM * DM;      // 1048576
    ushort_t* xb  = (ushort_t*)d_ws;
    ushort_t* Wqt = xb + TSZ;
    ushort_t* Wkt = Wqt + WSZ;
    ushort_t* Wvt = Wkt + WSZ;
    ushort_t* Wot = Wvt + WSZ;
    ushort_t* qbp = Wot + WSZ;
    ushort_t* kbp = qbp + TSZ;
    ushort_t* vtp = kbp + TSZ;
    ushort_t* ctxb = vtp + TSZ;

    // attn partials alias regions dead by the time attn runs.
    ushort_t* opart = xb;
    float* lpart = (float*)Wqt;

    conv_all<<<3072, 256, 0, stream>>>(x, xb, Wq, Wk, Wv, Wo, Wqt, Wkt, Wvt, Wot);

    mfma_gemm_qkv<<<dim3(DM / BN, MROWS / BM, 3), 256, 0, stream>>>(
        xb, Wqt, Wkt, Wvt, bq, bk, bv, qbp, kbp, vtp);

    attn_mfma<<<dim3(BATCH * NH, 48), 256, 0, stream>>>(
        qbp, kbp, vtp, ctxb, opart, lpart);
    attn_reduce<<<dim3(BATCH * NH, 16), 256, 0, stream>>>(opart, lpart, ctxb);

    mfma_gemm_out<<<dim3(DM / BN, MROWS / BM), 256, 0, stream>>>(ctxb, Wot, bo, out);
}

// Round 19
// 110.577 us; speedup vs baseline: 1.0941x; 1.0108x over previous
//
#include <hip/hip_runtime.h>
#include <hip/hip_bf16.h>
#include <math.h>

// Problem constants
constexpr int DM = 1024;
constexpr int SEQ = 2048;
constexpr int BATCH = 2;
constexpr int NH = 16;
constexpr int DH = 64;
constexpr int MROWS = BATCH * SEQ;  // 4096
constexpr float SCALE = 0.125f;

typedef __attribute__((ext_vector_type(8))) short short8;
typedef __attribute__((ext_vector_type(4))) float f32x4;
typedef unsigned short ushort_t;

__device__ __forceinline__ unsigned short f2b(float f) {
    __hip_bfloat16 h = __float2bfloat16(f);
    return __builtin_bit_cast(unsigned short, h);
}
__device__ __forceinline__ float b2f(unsigned short u) {
    unsigned int t = ((unsigned int)u) << 16;
    return __builtin_bit_cast(float, t);
}
// v_cvt_pk_bf16_f32: D = {bf16(hi) : bf16(lo)} (no builtin on gfx950 -> asm)
__device__ __forceinline__ unsigned int cvtpk_bf16(float lo, float hi) {
    unsigned int r;
    asm("v_cvt_pk_bf16_f32 %0, %1, %2" : "=v"(r) : "v"(lo), "v"(hi));
    return r;
}
// v_mfma_f32_16x16x16_bf16: A,B = 4 bf16 (2 VGPRs); C/D = 4 f32.
__device__ __forceinline__ f32x4 mfma16_bf16(uint2 a, uint2 b, f32x4 c) {
    asm("v_mfma_f32_16x16x16_bf16 %0, %1, %2, %0"
        : "+v"(c) : "v"(a), "v"(b));
    return c;
}

__device__ __forceinline__ void gload16(const ushort_t* g, ushort_t* l) {
    __builtin_amdgcn_global_load_lds(
        (const __attribute__((address_space(1))) void*)g,
        (__attribute__((address_space(3))) void*)l, 16, 0, 0);
}

// ---------------- merged converter: x -> bf16, W -> transposed bf16 ---------
// blocks [0, 2048): conv_x; blocks [2048, 3072): conv_w (16 x 16 x 4).
__global__ __launch_bounds__(256) void conv_all(
    const float* __restrict__ x, ushort_t* __restrict__ xb,
    const float* __restrict__ Wq, const float* __restrict__ Wk,
    const float* __restrict__ Wv, const float* __restrict__ Wo,
    ushort_t* __restrict__ Wqt, ushort_t* __restrict__ Wkt,
    ushort_t* __restrict__ Wvt, ushort_t* __restrict__ Wot) {
    const int bid = blockIdx.x;
    if (bid < 2048) {
        const size_t idx = (size_t)bid * 256 + threadIdx.x;
        const float4* src = (const float4*)(x + idx * 8);
        float4 a = src[0], b = src[1];
        short8 v;
        v[0] = (short)f2b(a.x); v[1] = (short)f2b(a.y);
        v[2] = (short)f2b(a.z); v[3] = (short)f2b(a.w);
        v[4] = (short)f2b(b.x); v[5] = (short)f2b(b.y);
        v[6] = (short)f2b(b.z); v[7] = (short)f2b(b.w);
        *(short8*)(xb + idx * 8) = v;
        return;
    }
    const int wid = bid - 2048;
    const int z = wid >> 8;
    const int rem = wid & 255;
    const float* W; ushort_t* Wt;
    switch (z) {
        case 0:  W = Wq; Wt = Wqt; break;
        case 1:  W = Wk; Wt = Wkt; break;
        case 2:  W = Wv; Wt = Wvt; break;
        default: W = Wo; Wt = Wot; break;
    }
    __shared__ float L[64][65];
    const int n0 = (rem & 15) * 64, k0 = (rem >> 4) * 64;
    const int t = threadIdx.x;
    const int tr = t >> 4, tc4 = (t & 15) * 4;
#pragma unroll
    for (int i = 0; i < 4; ++i) {
        int kk = tr + i * 16;
        float4 v = *(const float4*)&W[(size_t)(k0 + kk) * DM + n0 + tc4];
        L[kk][tc4 + 0] = v.x; L[kk][tc4 + 1] = v.y;
        L[kk][tc4 + 2] = v.z; L[kk][tc4 + 3] = v.w;
    }
    __syncthreads();
#pragma unroll
    for (int i = 0; i < 4; ++i) {
        int nn = tr + i * 16;
        ushort4 u;
        u.x = f2b(L[tc4 + 0][nn]); u.y = f2b(L[tc4 + 1][nn]);
        u.z = f2b(L[tc4 + 2][nn]); u.w = f2b(L[tc4 + 3][nn]);
        *(ushort4*)&Wt[(size_t)(n0 + nn) * DM + k0 + tc4] = u;
    }
}

// ---------------- MFMA GEMM core: 128x128 tile, BK=32, triple-buffered -------
// Counted-vmcnt pipeline (T4): per K-step wait vmcnt(4) (only the OLDEST
// stage drained), raw s_barrier, issue stage kt+2, then ds_read+MFMA.
// LDS superrow swizzle: buffer = 64 superrows (2 rows) x 8 slots x 16B.
#define BM 128
#define BN 128
#define BKK 32
#define NKT (DM / BKK)   // 32

__device__ __forceinline__ void stage_tile(const ushort_t* __restrict__ A,
                                           const ushort_t* __restrict__ B,
                                           int row0, int col0, int kt,
                                           ushort_t* As, ushort_t* Bs, int tid) {
#pragma unroll
    for (int i = 0; i < 2; ++i) {
        int f = i * 256 + tid;                    // [0,512)
        int sr = f >> 3, p = f & 7;
        int u = p ^ (sr & 7);
        int r = 2 * sr + (u >> 2);                // inverse-swizzled source
        int c = u & 3;
        gload16(&A[(size_t)(row0 + r) * DM + kt * BKK + c * 8], &As[f * 8]);
        gload16(&B[(size_t)(col0 + r) * DM + kt * BKK + c * 8], &Bs[f * 8]);
    }
}

__device__ __forceinline__ void mfma_core(const ushort_t* __restrict__ A,
                                          const ushort_t* __restrict__ B,
                                          int row0, int col0,
                                          ushort_t* smem, f32x4 (&acc)[4][4]) {
    const int tid = threadIdx.x;
    const int wave = tid >> 6, lane = tid & 63;
    const int lg = lane >> 4, ln = lane & 15;
    const int wr = wave >> 1, wc = wave & 1;

    stage_tile(A, B, row0, col0, 0, smem, smem + 4096, tid);
    __builtin_amdgcn_sched_barrier(0);
    stage_tile(A, B, row0, col0, 1, smem + 8192, smem + 12288, tid);

    for (int kt = 0; kt < NKT; ++kt) {
        if (kt + 1 < NKT)
            asm volatile("s_waitcnt vmcnt(4)" ::: "memory");
        else
            asm volatile("s_waitcnt vmcnt(0)" ::: "memory");
        __builtin_amdgcn_s_barrier();

        if (kt + 2 < NKT) {
            ushort_t* An = smem + ((kt + 2) % 3) * 8192;
            stage_tile(A, B, row0, col0, kt + 2, An, An + 4096, tid);
        }

        const ushort_t* As = smem + (kt % 3) * 8192;
        const ushort_t* Bs = As + 4096;
        short8 af[4], bf[4];
#pragma unroll
        for (int mi = 0; mi < 4; ++mi) {
            int r = wr * 64 + mi * 16 + ln;
            int sr = r >> 1;
            int p = (((r & 1) << 2) | lg) ^ (sr & 7);
            af[mi] = *(const short8*)&As[sr * 64 + p * 8];
        }
#pragma unroll
        for (int ni = 0; ni < 4; ++ni) {
            int r = wc * 64 + ni * 16 + ln;
            int sr = r >> 1;
            int p = (((r & 1) << 2) | lg) ^ (sr & 7);
            bf[ni] = *(const short8*)&Bs[sr * 64 + p * 8];
        }
        __builtin_amdgcn_s_setprio(1);
#pragma unroll
        for (int mi = 0; mi < 4; ++mi)
#pragma unroll
            for (int ni = 0; ni < 4; ++ni)
                acc[mi][ni] = __builtin_amdgcn_mfma_f32_16x16x32_bf16(
                    af[mi], bf[ni], acc[mi][ni], 0, 0, 0);
        __builtin_amdgcn_s_setprio(0);
    }
}

// QKV: z=0 -> qb [B,H,S,DH]; z=1 -> kb; z=2 -> vtb [B,H,DH,S]; all bf16 +bias.
// Partial RoPE (rot dim 16) fused into the q/k scatter.
__global__ __launch_bounds__(256) void mfma_gemm_qkv(
    const ushort_t* __restrict__ xb,
    const ushort_t* __restrict__ Wqt, const ushort_t* __restrict__ Wkt,
    const ushort_t* __restrict__ Wvt,
    const float* __restrict__ bq, const float* __restrict__ bk,
    const float* __restrict__ bv,
    ushort_t* __restrict__ qb, ushort_t* __restrict__ kb,
    ushort_t* __restrict__ vtb) {
    const ushort_t* W; const float* bias;
    if (blockIdx.z == 0)      { W = Wqt; bias = bq; }
    else if (blockIdx.z == 1) { W = Wkt; bias = bk; }
    else                      { W = Wvt; bias = bv; }

    const int row0 = blockIdx.y * BM;
    const int col0 = blockIdx.x * BN;
    __shared__ ushort_t smem[24576];   // 48 KB: 3 stage buffers; Cs aliases
    f32x4 acc[4][4] = {};
    mfma_core(xb, W, row0, col0, smem, acc);

    const int tid = threadIdx.x;
    const int wave = tid >> 6, lane = tid & 63;
    const int lg = lane >> 4, ln = lane & 15;
    const int wr = wave >> 1, wc = wave & 1;
    const bool isV = (blockIdx.z == 2);

    __syncthreads();
    ushort_t* Cs = smem;
#pragma unroll
    for (int mi = 0; mi < 4; ++mi)
#pragma unroll
        for (int ni = 0; ni < 4; ++ni)
#pragma unroll
            for (int r = 0; r < 4; ++r) {
                int mrel = wr * 64 + mi * 16 + lg * 4 + r;
                int nrel = wc * 64 + ni * 16 + ln;
                float v = acc[mi][ni][r] + bias[col0 + nrel];
                Cs[isV ? (nrel * 128 + mrel) : (mrel * 128 + nrel)] = f2b(v);
            }
    __syncthreads();

    if (!isV) {
        ushort_t* out = (blockIdx.z == 0) ? qb : kb;
#pragma unroll
        for (int i = 0; i < 8; ++i) {
            int f = i * 256 + tid;
            int rrow = f >> 4, c8 = f & 15;
            int m = row0 + rrow;
            int b = m >> 11, s = m & (SEQ - 1);
            int n = col0 + c8 * 8;
            int h = n >> 6, d = n & 63;
            short8 val;
            if (d < 16) {
                const ushort_t* base = &Cs[rrow * 128 + (c8 & 8) * 8];
                const bool hi = (d >= 8);
#pragma unroll
                for (int j = 0; j < 8; ++j) {
                    float t1 = b2f(base[j]);
                    float t2 = b2f(base[8 + j]);
                    float invf = __expf(-(float)j * 1.1512925465f); // ln(1e4)/8
                    float ang = (float)s * invf;
                    float c_, si_;
                    __sincosf(ang, &si_, &c_);
                    val[j] = (short)f2b(hi ? (t1 * si_ + t2 * c_)
                                           : (t1 * c_ - t2 * si_));
                }
            } else {
                val = *(const short8*)&Cs[rrow * 128 + c8 * 8];
            }
            *(short8*)&out[((size_t)((b * NH + h) * SEQ) + s) * DH + d] = val;
        }
    } else {
#pragma unroll
        for (int i = 0; i < 8; ++i) {
            int f = i * 256 + tid;
            int nrow = f >> 4, c8 = f & 15;
            int n = col0 + nrow;
            int h = n >> 6, d = n & 63;
            int m = row0 + c8 * 8;
            int b = m >> 11, s = m & (SEQ - 1);
            *(short8*)&vtb[((size_t)((b * NH + h) * DH) + d) * SEQ + s] =
                *(const short8*)&Cs[nrow * 128 + c8 * 8];
        }
    }
}

// Output projection: A = ctxb bf16 [M][DM], B = Wot, out fp32 [M][DM] + bo.
__global__ __launch_bounds__(256) void mfma_gemm_out(
    const ushort_t* __restrict__ ctxb, const ushort_t* __restrict__ Wot,
    const float* __restrict__ bo, float* __restrict__ out) {
    const int row0 = blockIdx.y * BM;
    const int col0 = blockIdx.x * BN;
    __shared__ ushort_t smem[24576];
    f32x4 acc[4][4] = {};
    mfma_core(ctxb, Wot, row0, col0, smem, acc);

    const int tid = threadIdx.x;
    const int wave = tid >> 6, lane = tid & 63;
    const int lg = lane >> 4, ln = lane & 15;
    const int wr = wave >> 1, wc = wave & 1;
#pragma unroll
    for (int mi = 0; mi < 4; ++mi)
#pragma unroll
        for (int ni = 0; ni < 4; ++ni)
#pragma unroll
            for (int r = 0; r < 4; ++r) {
                int m = row0 + wr * 64 + mi * 16 + lg * 4 + r;
                int n = col0 + wc * 64 + ni * 16 + ln;
                out[(size_t)m * DM + n] = acc[mi][ni][r] + bo[n];
            }
}

// ---------------- Causal flash attention, k-split, K-single / V-double ------
// R18 structure; l computed ON THE MATRIX PIPE: l5 = mfma16(P, ones) gives
// row-sums of P in the same register layout as o (q = lg*4+r), deleting the
// 16 scalar adds/step and ALL epilogue cross-lane shuffles.
//   y in [0,16):  qt = 16+y,  tiles [0,16)      -> partial chunk 0
//   y in [16,32): qt = 47-y,  tiles [16,qt+1)   -> partial chunk 1
//   y in [32,48): qt = 47-y,  tiles [0,qt+1)    -> direct ctx write
#define AQT 64
#define AKT 64
#define NQT (SEQ / AQT)   // 32

__global__ __launch_bounds__(256) void attn_mfma(
    const ushort_t* __restrict__ qb, const ushort_t* __restrict__ kb,
    const ushort_t* __restrict__ vtb, ushort_t* __restrict__ ctxb,
    ushort_t* __restrict__ opart, float* __restrict__ lpart) {
    constexpr float C1 = 0.18033688f;        // SCALE * log2(e)
    constexpr float M2 = 1.44269504f;        // C1 * 8 (score bound 8 sigma)
    const int bh = blockIdx.x;
    const int y = blockIdx.y;

    int qt, t0, t1, chunk;
    if (y < 16)      { qt = 16 + y;  t0 = 0;  t1 = 16;     chunk = 0; }
    else if (y < 32) { qt = 47 - y;  t0 = 16; t1 = qt + 1; chunk = 1; }
    else             { qt = 47 - y;  t0 = 0;  t1 = qt + 1; chunk = -1; }
    const int q0 = qt * AQT;

    const int tid = threadIdx.x;
    const int wave = tid >> 6;
    const int lane = tid & 63;
    const int lg = lane >> 4;
    const int ln = lane & 15;

    __shared__ ushort_t KT[64 * 64];      // K single buffer: 8 KB
    __shared__ ushort_t VT[2][64 * 64];   // V double buffer: 16 KB

    const ushort_t* kbase = kb + (size_t)bh * SEQ * DH;
    const ushort_t* vbase = vtb + (size_t)bh * DH * SEQ;
    const int b = bh >> 4, h = bh & 15;

    const ushort_t* qrow = qb + ((size_t)bh * SEQ + q0 + wave * 16 + ln) * DH;
    short8 qf0 = *(const short8*)&qrow[lg * 8];
    short8 qf1 = *(const short8*)&qrow[32 + lg * 8];

    f32x4 o[4];
#pragma unroll
    for (int nt = 0; nt < 4; nt++) o[nt] = f32x4{0.f, 0.f, 0.f, 0.f};
    f32x4 l5 = f32x4{0.f, 0.f, 0.f, 0.f};    // row-sum acc: l for q=lg*4+r
    const uint2 ones = {0x3F803F80u, 0x3F803F80u};  // 4 x bf16(1.0)

    // prologue: stage tile t0 (K->KT, V->VT[0])
#pragma unroll
    for (int i = 0; i < 2; i++) {
        int f = i * 256 + tid;
        int r = f >> 3, p = f & 7, c = p ^ (r & 7);
        gload16(&kbase[(size_t)(t0 * AKT + r) * DH + c * 8], &KT[f * 8]);
        gload16(&vbase[(size_t)r * SEQ + t0 * AKT + c * 8], &VT[0][f * 8]);
    }

    int cur = 0;
    for (int t = t0; t < t1; ++t) {
        __syncthreads();   // staging for tile t drained & visible

        // ---- swapped QK^T: st[kt][r] = S[key=16kt+lg*4+r][q=ln]
        float st[4][4];
        __builtin_amdgcn_s_setprio(1);
#pragma unroll
        for (int kt = 0; kt < 4; kt++) {
            f32x4 acc = f32x4{0.f, 0.f, 0.f, 0.f};
            int krow = kt * 16 + ln;
            short8 b0 = *(const short8*)&KT[krow * 64 + ((lg ^ (krow & 7)) * 8)];
            short8 b1 = *(const short8*)&KT[krow * 64 + (((4 + lg) ^ (krow & 7)) * 8)];
            acc = __builtin_amdgcn_mfma_f32_16x16x32_bf16(b0, qf0, acc, 0, 0, 0);
            acc = __builtin_amdgcn_mfma_f32_16x16x32_bf16(b1, qf1, acc, 0, 0, 0);
#pragma unroll
            for (int r = 0; r < 4; r++) st[kt][r] = acc[r];
        }
        __builtin_amdgcn_s_setprio(0);

        __syncthreads();   // all waves done reading KT -> safe to overwrite

        // issue next tile's staging NOW; flies under softmax + PV
        if (t + 1 < t1) {
            const int nb0 = (t + 1) * AKT;
            const int nxt = cur ^ 1;
#pragma unroll
            for (int i = 0; i < 2; i++) {
                int f = i * 256 + tid;
                int r = f >> 3, p = f & 7, c = p ^ (r & 7);
                gload16(&kbase[(size_t)(nb0 + r) * DH + c * 8], &KT[f * 8]);
                gload16(&vbase[(size_t)r * SEQ + nb0 + c * 8], &VT[nxt][f * 8]);
            }
        }

        // causal mask only on the diagonal tile (t == qt; never in chunk 0)
        if (t == qt) {
            const int qrel = wave * 16 + ln;
#pragma unroll
            for (int kt = 0; kt < 4; kt++)
#pragma unroll
                for (int r = 0; r < 4; r++)
                    if (kt * 16 + lg * 4 + r > qrel) st[kt][r] = -1e30f;
        }

        // ---- fixed-max softmax: p = exp2(C1*s - M2); P packed in registers
        uint2 pkq[4];
#pragma unroll
        for (int kt = 0; kt < 4; kt++) {
            float pv[4];
#pragma unroll
            for (int r = 0; r < 4; r++)
                pv[r] = exp2f(fmaf(C1, st[kt][r], -M2));
            pkq[kt].x = cvtpk_bf16(pv[0], pv[1]);
            pkq[kt].y = cvtpk_bf16(pv[2], pv[3]);
        }

        // ---- PV + l row-sum, all on the matrix pipe
        __builtin_amdgcn_s_setprio(1);
#pragma unroll
        for (int kt = 0; kt < 4; kt++)
            l5 = mfma16_bf16(pkq[kt], ones, l5);   // l[q] += sum_k P[q][k]
#pragma unroll
        for (int nt = 0; nt < 4; nt++) {
            int vrow = nt * 16 + ln;
#pragma unroll
            for (int kt = 0; kt < 4; kt++) {
                int chunk16 = (2 * kt + (lg >> 1)) ^ (vrow & 7);
                uint2 vb = *(const uint2*)&VT[cur][vrow * 64 + chunk16 * 8 + (lg & 1) * 4];
                o[nt] = mfma16_bf16(pkq[kt], vb, o[nt]);
            }
        }
        __builtin_amdgcn_s_setprio(0);

        cur ^= 1;
    }

    // ---- epilogue: l5[r] is l for q = wave*16 + lg*4 + r (no shuffles)
    if (chunk >= 0) {
        // partial: write bf16 o (undivided) + f32 l
        const int pid = ((bh << 4) + (qt - 16)) * 2 + chunk;
        if (ln == 0) {
#pragma unroll
            for (int r = 0; r < 4; r++)
                lpart[pid * 64 + wave * 16 + lg * 4 + r] = l5[r];
        }
        ushort_t* ob = opart + (size_t)pid * 4096;
#pragma unroll
        for (int r = 0; r < 4; r++) {
            int qrel = wave * 16 + lg * 4 + r;
#pragma unroll
            for (int nt = 0; nt < 4; nt++)
                ob[qrel * 64 + nt * 16 + ln] = f2b(o[nt][r]);
        }
    } else {
#pragma unroll
        for (int r = 0; r < 4; r++) {
            float invl = 1.f / l5[r];
            int qg = q0 + wave * 16 + lg * 4 + r;
            ushort_t* op = ctxb + ((size_t)(b * SEQ + qg)) * DM + h * DH;
#pragma unroll
            for (int nt = 0; nt < 4; nt++)
                op[nt * 16 + ln] = f2b(o[nt][r] * invl);
        }
    }
}

// Combine the two partials for qt >= 16: ctx = (o0 + o1) / (l0 + l1).
__global__ __launch_bounds__(256) void attn_reduce(
    const ushort_t* __restrict__ opart, const float* __restrict__ lpart,
    ushort_t* __restrict__ ctxb) {
    const int bh = blockIdx.x;             // 0..31
    const int qt = 16 + blockIdx.y;        // 16..31
    const int tid = threadIdx.x;
    const int q = tid >> 2;                // 0..63
    const int d0 = (tid & 3) * 16;         // 0,16,32,48

    const int pid0 = ((bh << 4) + (qt - 16)) * 2;
    const ushort_t* o0 = opart + (size_t)pid0 * 4096 + q * 64 + d0;
    const ushort_t* o1 = opart + (size_t)(pid0 + 1) * 4096 + q * 64 + d0;
    const float inv = 1.f / (lpart[pid0 * 64 + q] + lpart[(pid0 + 1) * 64 + q]);

    const int b = bh >> 4, h = bh & 15;
    ushort_t* op = ctxb + ((size_t)(b * SEQ + qt * 64 + q)) * DM + h * DH + d0;
#pragma unroll
    for (int half = 0; half < 2; ++half) {
        short8 a = *(const short8*)&o0[half * 8];
        short8 c = *(const short8*)&o1[half * 8];
        short8 r;
#pragma unroll
        for (int j = 0; j < 8; ++j)
            r[j] = (short)f2b((b2f((unsigned short)a[j]) +
                               b2f((unsigned short)c[j])) * inv);
        *(short8*)&op[half * 8] = r;
    }
}

// ---------------- launch ------------------------------------------------------
extern "C" void kernel_launch(void* const* d_in, const int* in_sizes, int n_in,
                              void* d_out, int out_size, void* d_ws, size_t ws_size,
                              hipStream_t stream) {
    const float* x  = (const float*)d_in[0];
    const float* Wq = (const float*)d_in[1];
    const float* bq = (const float*)d_in[2];
    const float* Wk = (const float*)d_in[3];
    const float* bk = (const float*)d_in[4];
    const float* Wv = (const float*)d_in[5];
    const float* bv = (const float*)d_in[6];
    const float* Wo = (const float*)d_in[7];
    const float* bo = (const float*)d_in[8];
    float* out = (float*)d_out;

    constexpr size_t TSZ = (size_t)MROWS * DM;   // 4194304
    constexpr size_t WSZ = (size_t)DM * DM;      // 1048576
    ushort_t* xb  = (ushort_t*)d_ws;
    ushort_t* Wqt = xb + TSZ;
    ushort_t* Wkt = Wqt + WSZ;
    ushort_t* Wvt = Wkt + WSZ;
    ushort_t* Wot = Wvt + WSZ;
    ushort_t* qbp = Wot + WSZ;
    ushort_t* kbp = qbp + TSZ;
    ushort_t* vtp = kbp + TSZ;
    ushort_t* ctxb = vtp + TSZ;

    // attn partials alias regions dead by the time attn runs.
    ushort_t* opart = xb;
    float* lpart = (float*)Wqt;

    conv_all<<<3072, 256, 0, stream>>>(x, xb, Wq, Wk, Wv, Wo, Wqt, Wkt, Wvt, Wot);

    mfma_gemm_qkv<<<dim3(DM / BN, MROWS / BM, 3), 256, 0, stream>>>(
        xb, Wqt, Wkt, Wvt, bq, bk, bv, qbp, kbp, vtp);

    attn_mfma<<<dim3(BATCH * NH, 48), 256, 0, stream>>>(
        qbp, kbp, vtp, ctxb, opart, lpart);
    attn_reduce<<<dim3(BATCH * NH, 16), 256, 0, stream>>>(opart, lpart, ctxb);

    mfma_gemm_out<<<dim3(DM / BN, MROWS / BM), 256, 0, stream>>>(ctxb, Wot, bo, out);
}